// Round 4
// baseline (1049.391 us; speedup 1.0000x reference)
//
#include <hip/hip_runtime.h>

// Problem constants
#define T_LEN 120
#define H 128
#define FC1_STRIDE 15360 // T*H

// workspace layout (bytes)
#define OFF_WHH   0u        // [512][128] bf16, pre-scaled by gate constant
#define OFF_WXB   131072u   // [512][32]  bf16 (W_ih cols 0-3, bias col 4), pre-scaled
#define OFF_FC1W  163840u   // [128][15360] bf16 (rows >=100 zero)
#define OFF_FC1B  4096000u  // [128] f32 (zero-padded)

typedef short short8 __attribute__((ext_vector_type(8)));   // 8 bf16 in 4 VGPRs
typedef float f32x4 __attribute__((ext_vector_type(4)));
typedef unsigned int ui32x4 __attribute__((ext_vector_type(4)));

#define L2E 1.4426950408889634f
#define SWZ(r) (((((r) & 7) ^ (((r) >> 3) << 1))) << 4)
#define MFMA __builtin_amdgcn_mfma_f32_16x16x32_bf16
#define BAR() do { asm volatile("s_waitcnt lgkmcnt(0)" ::: "memory"); \
                   __builtin_amdgcn_s_barrier(); \
                   asm volatile("" ::: "memory"); } while (0)

__device__ __forceinline__ unsigned short f2bu(float f) {   // f32 -> bf16 (RNE)
  unsigned u = __builtin_bit_cast(unsigned, f);
  u += 0x7fffu + ((u >> 16) & 1u);
  return (unsigned short)(u >> 16);
}
__device__ __forceinline__ float gate_scale(int row) {
  // rows 0-127: i, 128-255: f, 256-383: g, 384-511: o
  return ((row >> 7) == 2) ? 2.0f * L2E : -L2E;
}

// ---- one-time weight conversion (single launch) ----
__global__ void prep_all(const float* __restrict__ W_ih, const float* __restrict__ W_hh,
                         const float* __restrict__ b_ih, const float* __restrict__ b_hh,
                         const float* __restrict__ fc1_w, const float* __restrict__ fc1_b,
                         unsigned char* __restrict__ ws) {
  if (blockIdx.x < 1024) {
    unsigned short* w = (unsigned short*)(ws + OFF_FC1W);
    int j = blockIdx.x >> 3;
    int c0 = ((blockIdx.x & 7) * 256 + threadIdx.x) * 8;
    if (c0 >= FC1_STRIDE) return;
    short8 v = {0, 0, 0, 0, 0, 0, 0, 0};
    if (j < 100) {
      const float* src = fc1_w + j * FC1_STRIDE + c0;
#pragma unroll
      for (int e = 0; e < 8; ++e) ((unsigned short*)&v)[e] = f2bu(src[e]);
    }
    *(short8*)(w + j * FC1_STRIDE + c0) = v;
  } else {
    unsigned short* whh = (unsigned short*)(ws + OFF_WHH);
    unsigned short* wxb = (unsigned short*)(ws + OFF_WXB);
    float* fb = (float*)(ws + OFF_FC1B);
    int tid = (blockIdx.x - 1024) * 256 + threadIdx.x;
    const int nt = 8 * 256;
    for (int i = tid; i < 512 * 128; i += nt) {
      int row = i >> 7;
      whh[i] = f2bu(W_hh[i] * gate_scale(row));
    }
    for (int i = tid; i < 512 * 32; i += nt) {
      int j = i >> 5, k = i & 31;
      float s = gate_scale(j);
      float v = 0.f;
      if (k < 4) v = W_ih[j * 4 + k] * s;
      else if (k == 4) v = (b_ih[j] + b_hh[j]) * s;
      wxb[i] = f2bu(v);
    }
    for (int i = tid; i < 128; i += nt) fb[i] = (i < 100) ? fc1_b[i] : 0.f;
  }
}

// ---- fused persistent kernel: 256 blocks x 1024 threads (16 waves, 4/SIMD) ----
// Wave pair p (8 pairs) owns gate columns [16p,16p+16). Even-role wave: gates i,f.
// Odd-role wave: gates g,o + c/h state. Role = bit2 of wave id so each SIMD
// hosts 2 even + 2 odd waves (trans-pipe balance).
__global__ __launch_bounds__(1024, 4)
void lstm_fused(const float* __restrict__ x, const float* __restrict__ h0,
                const float* __restrict__ c0, const float* __restrict__ fc2_w,
                const float* __restrict__ fc2_b, const unsigned char* __restrict__ ws,
                float* __restrict__ out) {
  __shared__ __align__(16) unsigned char xab[T_LEN * 256];      // packed xa frags; reused as hid[16][132] f32 in epilogue
  __shared__ __align__(16) unsigned char h_lds[2 * 4096];       // double-buffered bf16 h (16 rows x 128)
  __shared__ __align__(16) float pex[8 * 512];                  // pair exchange: pair p, lane l -> 8 f32
  __shared__ __align__(16) float fc2w_s[1000];
  __shared__ float fc2b_s[10];
  __shared__ float logit_s[16 * 12];

  const int tid = threadIdx.x;
  const int W = tid >> 6;
  const int l = tid & 63;
  const int lq = l >> 4;
  const int lc = l & 15;
  const int erole = (W >> 2) & 1;            // 0: gates i,f   1: gates g,o
  const int p = (W & 3) | ((W >> 3) << 2);   // pair 0..7
  const int r0 = blockIdx.x * 16;
  const int hcol = p * 16 + lc;              // gate/h column (also fc1 row index)

  const unsigned short* Whh = (const unsigned short*)(ws + OFF_WHH);
  const unsigned short* Wxb = (const unsigned short*)(ws + OFF_WXB);
  const unsigned short* FC1 = (const unsigned short*)(ws + OFF_FC1W);
  const float* FC1B = (const float*)(ws + OFF_FC1B);

  // stage fc2 weights (read-only, used in epilogue)
  for (int i = tid; i < 1000; i += 1024) fc2w_s[i] = fc2_w[i];
  if (tid < 10) fc2b_s[tid] = fc2_b[tid];

  // pre-pack x A-fragments for all t: slot (t, row) = 16B short8
  // A_x[row][k]: k=0..3 -> x features, k=4 -> 1.0 (bias), k>=5 -> 0
  for (int i = tid; i < 16 * T_LEN; i += 1024) {
    int rr = i / T_LEN, t = i - rr * T_LEN;
    const float* xr = x + (r0 + rr) * (T_LEN * 4) + t * 4;
    f32x4 xv = *(const f32x4*)xr;
    unsigned w0 = (unsigned)f2bu(xv[0]) | ((unsigned)f2bu(xv[1]) << 16);
    unsigned w1 = (unsigned)f2bu(xv[2]) | ((unsigned)f2bu(xv[3]) << 16);
    ui32x4 pk = {w0, w1, 0x3f80u, 0u};
    *(ui32x4*)(xab + t * 256 + rr * 16) = pk;
  }
  // stage h0 -> buffer 1 (loop t=0 writes buffer 0)
  {
    int e = tid * 2;
    int r = e >> 7, c = e & 127;
    unsigned u = (unsigned)f2bu(h0[(r0 + r) * H + c]) |
                 ((unsigned)f2bu(h0[(r0 + r) * H + c + 1]) << 16);
    *(unsigned*)(h_lds + 4096 + r * 256 + ((2 * c) ^ SWZ(r))) = u;
  }
  // c0 lives on odd-role waves: lane owns rows lq*4+q, col hcol
  float c_reg[4] = {0.f, 0.f, 0.f, 0.f};
  if (erole) {
#pragma unroll
    for (int q = 0; q < 4; ++q) c_reg[q] = c0[(r0 + lq * 4 + q) * H + hcol];
  }

  // B fragments: this wave's 2 gates, full K (32 VGPRs) + x-part (8 VGPRs)
  short8 bhh[2][4], bxb[2];
#pragma unroll
  for (int g = 0; g < 2; ++g) {
    int n0 = (erole * 2 + g) * 128 + p * 16;
#pragma unroll
    for (int kk = 0; kk < 4; ++kk)
      bhh[g][kk] = *(const short8*)(Whh + (n0 + lc) * H + kk * 32 + lq * 8);
    bxb[g] = *(const short8*)(Wxb + (n0 + lc) * 32 + lq * 8);
  }
  // fc1: K-split across the pair (even: k in [0,64), odd: [64,128)), summed at end
  const unsigned short* fc1base = FC1 + hcol * FC1_STRIDE + erole * 64 + lq * 8;
  f32x4 facc = {0.f, 0.f, 0.f, 0.f};

  __syncthreads();

  // initial A fragments from h0 (buffer 1)
  short8 ha[4];
#pragma unroll
  for (int kk = 0; kk < 4; ++kk)
    ha[kk] = *(const short8*)(h_lds + 4096 + lc * 256 + ((kk * 64 + lq * 16) ^ SWZ(lc)));

  // xa for t=0 (lanes lq==0 carry data; others stay zero forever)
  short8 xa = {0, 0, 0, 0, 0, 0, 0, 0};
  if (lq == 0) xa = *(const short8*)(xab + lc * 16);

  const f32x4 zero4 = {0.f, 0.f, 0.f, 0.f};
  float* const pexp = pex + p * 512 + l * 8;
  const int slotA = (l & 1) << 2, slotB = ((l & 1) ^ 1) << 2;

  float tg[4], ov[4];

  for (int t = 0; t < T_LEN; ++t) {
    // fc1 B-frags for slice t (global; consumed at loop bottom ~1000cy later)
    const unsigned short* fp = fc1base + t * 128;
    short8 fbA = *(const short8*)(fp);
    short8 fbB = *(const short8*)(fp + 32);

    // gate chain: x-part then 4 K-frags (depth 5, two interleaved chains)
    f32x4 accA = MFMA(xa, bxb[0], zero4, 0, 0, 0);
    f32x4 accB = MFMA(xa, bxb[1], zero4, 0, 0, 0);
#pragma unroll
    for (int kk = 0; kk < 4; ++kk) {
      accA = MFMA(ha[kk], bhh[0][kk], accA, 0, 0, 0);
      accB = MFMA(ha[kk], bhh[1][kk], accB, 0, 0, 0);
    }

    if (!erole) {
      // even-role: si = sigmoid(xi), sf = sigmoid(xf); ship to partner via LDS
      f32x4 s01, s23;
#pragma unroll
      for (int q = 0; q < 4; ++q) {
        float ea = __builtin_amdgcn_exp2f(accA[q]);   // e^{-xi}
        float eb = __builtin_amdgcn_exp2f(accB[q]);   // e^{-xf}
        float a = 1.f + ea, b = 1.f + eb;
        float rab = __builtin_amdgcn_rcpf(a * b);
        float si = b * rab, sf = a * rab;
        if (q < 2) { s01[q * 2] = si; s01[q * 2 + 1] = sf; }
        else       { s23[(q - 2) * 2] = si; s23[(q - 2) * 2 + 1] = sf; }
      }
      *(f32x4*)(pexp + slotA) = s01;
      *(f32x4*)(pexp + slotB) = s23;
    } else {
      // odd-role: tg = tanh(xg), ov = sigmoid(xo)
#pragma unroll
      for (int q = 0; q < 4; ++q) {
        float ec = __builtin_amdgcn_exp2f(accA[q]);   // e^{2xg}
        float ed = __builtin_amdgcn_exp2f(accB[q]);   // e^{-xo}
        float d = 1.f + ec, e1 = 1.f + ed;
        float rde = __builtin_amdgcn_rcpf(d * e1);
        tg[q] = 1.f - 2.f * (e1 * rde);
        ov[q] = d * rde;
      }
    }

    BAR();   // B1: si/sf visible

    if (erole) {
      f32x4 s01 = *(const f32x4*)(pexp + slotA);
      f32x4 s23 = *(const f32x4*)(pexp + slotB);
      unsigned char* hw = h_lds + (t & 1) * 4096;
#pragma unroll
      for (int q = 0; q < 4; ++q) {
        float si = (q < 2) ? s01[q * 2] : s23[(q - 2) * 2];
        float sf = (q < 2) ? s01[q * 2 + 1] : s23[(q - 2) * 2 + 1];
        float cn = sf * c_reg[q] + si * tg[q];
        c_reg[q] = cn;
        float et = __builtin_amdgcn_exp2f(2.8853900817779268f * cn);
        float hv = ov[q] * (1.f - 2.f * __builtin_amdgcn_rcpf(1.f + et));
        int r = lq * 4 + q;
        *(unsigned short*)(hw + r * 256 + ((2 * hcol) ^ SWZ(r))) = f2bu(hv);
      }
    }
    // prefetch next xa (xab is read-only; any placement OK)
    if (t + 1 < T_LEN && lq == 0)
      xa = *(const short8*)(xab + (t + 1) * 256 + lc * 16);

    BAR();   // B2: h_t complete

    // reload h_t fragments; fc1 partial with NEW h and this step's fb
    unsigned char* hr = h_lds + (t & 1) * 4096;
#pragma unroll
    for (int kk = 0; kk < 4; ++kk)
      ha[kk] = *(const short8*)(hr + lc * 256 + ((kk * 64 + lq * 16) ^ SWZ(lc)));
    facc = MFMA(ha[erole * 2 + 0], fbA, facc, 0, 0, 0);
    facc = MFMA(ha[erole * 2 + 1], fbB, facc, 0, 0, 0);
  }

  // ---- fc1 pair-sum, bias+ReLU, fc2, log_softmax ----
  if (!erole) *(f32x4*)pexp = facc;
  BAR();
  if (erole) {
    f32x4 o = *(const f32x4*)pexp;
    float bias = FC1B[hcol];
    float* hid = (float*)xab;           // [16][132] padded
#pragma unroll
    for (int q = 0; q < 4; ++q) {
      float v = facc[q] + o[q] + bias;
      hid[(lq * 4 + q) * 132 + hcol] = v > 0.f ? v : 0.f;
    }
  }
  __syncthreads();
  if (tid < 160) {
    int r = tid & 15, k = tid >> 4;
    float* hid = (float*)xab;
    float a = fc2b_s[k];
#pragma unroll 4
    for (int j = 0; j < 100; ++j) a += hid[r * 132 + j] * fc2w_s[k * 100 + j];
    logit_s[r * 12 + k] = a;
  }
  __syncthreads();
  if (tid < 16) {
    int r = tid;
    float m = logit_s[r * 12];
#pragma unroll
    for (int k = 1; k < 10; ++k) m = fmaxf(m, logit_s[r * 12 + k]);
    float s = 0.f;
#pragma unroll
    for (int k = 0; k < 10; ++k)
      s += __builtin_amdgcn_exp2f(L2E * (logit_s[r * 12 + k] - m));
    float ls = __builtin_amdgcn_logf(s) * 0.6931471805599453f;
#pragma unroll
    for (int k = 0; k < 10; ++k)
      out[(r0 + r) * 10 + k] = logit_s[r * 12 + k] - m - ls;
  }
}

extern "C" void kernel_launch(void* const* d_in, const int* in_sizes, int n_in,
                              void* d_out, int out_size, void* d_ws, size_t ws_size,
                              hipStream_t stream) {
  const float* x     = (const float*)d_in[0];
  const float* h0    = (const float*)d_in[1];
  const float* c0    = (const float*)d_in[2];
  const float* W_ih  = (const float*)d_in[3];
  const float* W_hh  = (const float*)d_in[4];
  const float* b_ih  = (const float*)d_in[5];
  const float* b_hh  = (const float*)d_in[6];
  const float* fc1_w = (const float*)d_in[7];
  const float* fc1_b = (const float*)d_in[8];
  const float* fc2_w = (const float*)d_in[9];
  const float* fc2_b = (const float*)d_in[10];
  float* out = (float*)d_out;
  unsigned char* ws = (unsigned char*)d_ws;

  prep_all<<<1032, 256, 0, stream>>>(W_ih, W_hh, b_ih, b_hh, fc1_w, fc1_b, ws);
  lstm_fused<<<256, 1024, 0, stream>>>(x, h0, c0, fc2_w, fc2_b, ws, out);
}

// Round 5
// 296.910 us; speedup vs baseline: 3.5344x; 3.5344x over previous
//
#include <hip/hip_runtime.h>

// Problem constants
#define T_LEN 120
#define H 128
#define FC1_STRIDE 15360 // T*H

// workspace layout (bytes)
#define OFF_WHH   0u        // [512][128] bf16, pre-scaled by gate constant
#define OFF_WXB   131072u   // [512][32]  bf16 (W_ih cols 0-3, bias col 4), pre-scaled
#define OFF_FC1W  163840u   // [128][15360] bf16 (rows >=100 zero)
#define OFF_FC1B  4096000u  // [128] f32 (zero-padded)

typedef short short8 __attribute__((ext_vector_type(8)));   // 8 bf16 in 4 VGPRs
typedef float f32x4 __attribute__((ext_vector_type(4)));
typedef unsigned int ui32x4 __attribute__((ext_vector_type(4)));

#define L2E 1.4426950408889634f
#define SWZ(r) (((((r) & 7) ^ (((r) >> 3) << 1))) << 4)
#define MFMA __builtin_amdgcn_mfma_f32_16x16x32_bf16
#define BAR() do { asm volatile("s_waitcnt lgkmcnt(0)" ::: "memory"); \
                   __builtin_amdgcn_s_barrier(); \
                   asm volatile("" ::: "memory"); } while (0)

__device__ __forceinline__ unsigned short f2bu(float f) {   // f32 -> bf16 (RNE)
  unsigned u = __builtin_bit_cast(unsigned, f);
  u += 0x7fffu + ((u >> 16) & 1u);
  return (unsigned short)(u >> 16);
}
__device__ __forceinline__ float gate_scale(int row) {
  // rows 0-127: i, 128-255: f, 256-383: g, 384-511: o
  return ((row >> 7) == 2) ? 2.0f * L2E : -L2E;
}

// ---- one-time weight conversion (single launch) ----
__global__ void prep_all(const float* __restrict__ W_ih, const float* __restrict__ W_hh,
                         const float* __restrict__ b_ih, const float* __restrict__ b_hh,
                         const float* __restrict__ fc1_w, const float* __restrict__ fc1_b,
                         unsigned char* __restrict__ ws) {
  if (blockIdx.x < 1024) {
    unsigned short* w = (unsigned short*)(ws + OFF_FC1W);
    int j = blockIdx.x >> 3;
    int c0 = ((blockIdx.x & 7) * 256 + threadIdx.x) * 8;
    if (c0 >= FC1_STRIDE) return;
    short8 v = {0, 0, 0, 0, 0, 0, 0, 0};
    if (j < 100) {
      const float* src = fc1_w + j * FC1_STRIDE + c0;
#pragma unroll
      for (int e = 0; e < 8; ++e) ((unsigned short*)&v)[e] = f2bu(src[e]);
    }
    *(short8*)(w + j * FC1_STRIDE + c0) = v;
  } else {
    unsigned short* whh = (unsigned short*)(ws + OFF_WHH);
    unsigned short* wxb = (unsigned short*)(ws + OFF_WXB);
    float* fb = (float*)(ws + OFF_FC1B);
    int tid = (blockIdx.x - 1024) * 256 + threadIdx.x;
    const int nt = 8 * 256;
    for (int i = tid; i < 512 * 128; i += nt) {
      int row = i >> 7;
      whh[i] = f2bu(W_hh[i] * gate_scale(row));
    }
    for (int i = tid; i < 512 * 32; i += nt) {
      int j = i >> 5, k = i & 31;
      float s = gate_scale(j);
      float v = 0.f;
      if (k < 4) v = W_ih[j * 4 + k] * s;
      else if (k == 4) v = (b_ih[j] + b_hh[j]) * s;
      wxb[i] = f2bu(v);
    }
    for (int i = tid; i < 128; i += nt) fb[i] = (i < 100) ? fc1_b[i] : 0.f;
  }
}

// ---- fused persistent kernel: 256 blocks x 768 threads (12 waves, 3/SIMD) ----
// Waves 0-7: LSTM recurrence (R2 layout: wave w owns gate columns [16w,16w+16),
//            all 4 gates register-resident, activations + c/h state in regs).
// Waves 8-11: fc1 helpers — stream fc1_w t-slices from L2 and accumulate
//            hid = sum_t h_t @ fc1_w[:, t*128:+128]^T  (8 MFMA/step each).
__global__ __launch_bounds__(768)
void lstm_fused(const float* __restrict__ x, const float* __restrict__ h0,
                const float* __restrict__ c0, const float* __restrict__ fc2_w,
                const float* __restrict__ fc2_b, const unsigned char* __restrict__ ws,
                float* __restrict__ out) {
  __shared__ __align__(16) unsigned char xab[T_LEN * 256];   // packed x A-frags; reused as hid[16][132] f32 in epilogue
  __shared__ __align__(16) unsigned char h_lds[2 * 4096];    // double-buffered bf16 h (16 rows x 128, swizzled)
  __shared__ __align__(16) float fc2w_s[1000];
  __shared__ float fc2b_s[10];
  __shared__ float logit_s[16 * 12];

  const int tid = threadIdx.x;
  const int W = tid >> 6;         // wave 0..11
  const int l = tid & 63;
  const int lq = l >> 4;
  const int lc = l & 15;
  const int r0 = blockIdx.x * 16;
  const bool is_fc1 = (W >= 8);

  const unsigned short* Whh = (const unsigned short*)(ws + OFF_WHH);
  const unsigned short* Wxb = (const unsigned short*)(ws + OFF_WXB);
  const unsigned short* FC1 = (const unsigned short*)(ws + OFF_FC1W);
  const float* FC1B = (const float*)(ws + OFF_FC1B);

  // stage fc2 weights
  for (int i = tid; i < 1000; i += 768) fc2w_s[i] = fc2_w[i];
  if (tid < 10) fc2b_s[tid] = fc2_b[tid];

  // pre-pack x A-fragments for all t: slot (t,row) = 16B {x0,x1,x2,x3,1.0,0,0,0}
  for (int i = tid; i < 16 * T_LEN; i += 768) {
    int rr = i / T_LEN, t = i - rr * T_LEN;
    f32x4 xv = *(const f32x4*)(x + (r0 + rr) * (T_LEN * 4) + t * 4);
    unsigned w0 = (unsigned)f2bu(xv[0]) | ((unsigned)f2bu(xv[1]) << 16);
    unsigned w1 = (unsigned)f2bu(xv[2]) | ((unsigned)f2bu(xv[3]) << 16);
    ui32x4 pk = {w0, w1, 0x3f80u, 0u};
    *(ui32x4*)(xab + t * 256 + rr * 16) = pk;
  }
  // stage h0 -> buffer 1 (loop t=0 writes buffer 0)
  for (int i = tid; i < 1024; i += 768) {
    int e = i * 2;
    int r = e >> 7, c = e & 127;
    unsigned u = (unsigned)f2bu(h0[(r0 + r) * H + c]) |
                 ((unsigned)f2bu(h0[(r0 + r) * H + c + 1]) << 16);
    *(unsigned*)(h_lds + 4096 + r * 256 + ((2 * c) ^ SWZ(r))) = u;
  }

  // ---- per-role register state ----
  float c_reg[4] = {0.f, 0.f, 0.f, 0.f};
  short8 bhh[4][4], bxb[4];              // compute waves only
  short8 fb[2][4];                       // fc1 waves only
  f32x4 facc0 = {0.f, 0.f, 0.f, 0.f}, facc1 = {0.f, 0.f, 0.f, 0.f};
  const unsigned short* fc1p0 = nullptr;
  const unsigned short* fc1p1 = nullptr;
  int hcol = 0;

  if (!is_fc1) {
    hcol = W * 16 + lc;
#pragma unroll
    for (int q = 0; q < 4; ++q) c_reg[q] = c0[(r0 + lq * 4 + q) * H + hcol];
#pragma unroll
    for (int g = 0; g < 4; ++g) {
      int n0 = (g * 8 + W) * 16;
#pragma unroll
      for (int kk = 0; kk < 4; ++kk)
        bhh[g][kk] = *(const short8*)(Whh + (n0 + lc) * H + kk * 32 + lq * 8);
      bxb[g] = *(const short8*)(Wxb + (n0 + lc) * 32 + lq * 8);
    }
  } else {
    int j = W - 8;                       // fc1 wave j owns hid cols [32j, 32j+32)
    fc1p0 = FC1 + (32 * j + lc) * FC1_STRIDE + lq * 8;
    fc1p1 = FC1 + (32 * j + 16 + lc) * FC1_STRIDE + lq * 8;
  }

  __syncthreads();

  // initial A fragments from h0 (buffer 1); xa for t=0
  short8 ha[4];
  short8 xa = *(const short8*)(xab + lc * 16);
#pragma unroll
  for (int kk = 0; kk < 4; ++kk)
    ha[kk] = *(const short8*)(h_lds + 4096 + lc * 256 + ((kk * 64 + lq * 16) ^ SWZ(lc)));

  const f32x4 zero4 = {0.f, 0.f, 0.f, 0.f};

  for (int t = 0; t < T_LEN; ++t) {
    unsigned char* hb = h_lds + (t & 1) * 4096;

    if (is_fc1) {
      // stream this step's fc1 B-frags (consumed after the barrier)
      const unsigned short* p0 = fc1p0 + t * 128;
      const unsigned short* p1 = fc1p1 + t * 128;
#pragma unroll
      for (int kk = 0; kk < 4; ++kk) {
        fb[0][kk] = *(const short8*)(p0 + kk * 32);
        fb[1][kk] = *(const short8*)(p1 + kk * 32);
      }
    } else {
      // gates(t): xa chain-head then 4 ha frags (4 independent chains, depth 5)
      f32x4 acc0 = MFMA(xa, bxb[0], zero4, 0, 0, 0);
      f32x4 acc1 = MFMA(xa, bxb[1], zero4, 0, 0, 0);
      f32x4 acc2 = MFMA(xa, bxb[2], zero4, 0, 0, 0);
      f32x4 acc3 = MFMA(xa, bxb[3], zero4, 0, 0, 0);
#pragma unroll
      for (int kk = 0; kk < 4; ++kk) {
        acc0 = MFMA(ha[kk], bhh[0][kk], acc0, 0, 0, 0);
        acc1 = MFMA(ha[kk], bhh[1][kk], acc1, 0, 0, 0);
        acc2 = MFMA(ha[kk], bhh[2][kk], acc2, 0, 0, 0);
        acc3 = MFMA(ha[kk], bhh[3][kk], acc3, 0, 0, 0);
      }
      // activations (pre-scaled weights: exp2 direct; paired reciprocals)
#pragma unroll
      for (int q = 0; q < 4; ++q) {
        float ea = __builtin_amdgcn_exp2f(acc0[q]);   // e^{-xi}
        float eb = __builtin_amdgcn_exp2f(acc1[q]);   // e^{-xf}
        float ec = __builtin_amdgcn_exp2f(acc2[q]);   // e^{2xg}
        float ed = __builtin_amdgcn_exp2f(acc3[q]);   // e^{-xo}
        float a = 1.f + ea, b = 1.f + eb, d = 1.f + ec, e1 = 1.f + ed;
        float rab = __builtin_amdgcn_rcpf(a * b);
        float rde = __builtin_amdgcn_rcpf(d * e1);
        float iv = b * rab;
        float fv = a * rab;
        float gv = 1.f - 2.f * (e1 * rde);
        float ov = d * rde;
        float cn = fv * c_reg[q] + iv * gv;
        c_reg[q] = cn;
        float et = __builtin_amdgcn_exp2f(2.8853900817779268f * cn);
        float hv = ov * (1.f - 2.f * __builtin_amdgcn_rcpf(1.f + et));
        int r = lq * 4 + q;
        *(unsigned short*)(hb + r * 256 + ((2 * hcol) ^ SWZ(r))) = f2bu(hv);
      }
    }

    BAR();   // h_t complete (fc1 loads stay in flight on vmcnt)

    // all waves: read h_t fragments; prefetch next xa (compute waves use it)
#pragma unroll
    for (int kk = 0; kk < 4; ++kk)
      ha[kk] = *(const short8*)(hb + lc * 256 + ((kk * 64 + lq * 16) ^ SWZ(lc)));
    int tn = (t + 1 < T_LEN) ? t + 1 : t;
    xa = *(const short8*)(xab + tn * 256 + lc * 16);

    if (is_fc1) {
#pragma unroll
      for (int kk = 0; kk < 4; ++kk) {
        facc0 = MFMA(ha[kk], fb[0][kk], facc0, 0, 0, 0);
        facc1 = MFMA(ha[kk], fb[1][kk], facc1, 0, 0, 0);
      }
    }
  }

  // ---- epilogue: bias+ReLU -> fc2 -> log_softmax ----
  __syncthreads();                 // xab free for reuse as hid
  float* hid = (float*)xab;        // [16][132] padded
  if (is_fc1) {
    int j = W - 8;
    float b0 = FC1B[32 * j + lc];
    float b1 = FC1B[32 * j + 16 + lc];
#pragma unroll
    for (int q = 0; q < 4; ++q) {
      int r = lq * 4 + q;
      float v0 = facc0[q] + b0;
      float v1 = facc1[q] + b1;
      hid[r * 132 + 32 * j + lc] = v0 > 0.f ? v0 : 0.f;
      hid[r * 132 + 32 * j + 16 + lc] = v1 > 0.f ? v1 : 0.f;
    }
  }
  __syncthreads();
  if (tid < 160) {
    int r = tid & 15, k = tid >> 4;
    float a = fc2b_s[k];
#pragma unroll 4
    for (int j = 0; j < 100; ++j) a += hid[r * 132 + j] * fc2w_s[k * 100 + j];
    logit_s[r * 12 + k] = a;
  }
  __syncthreads();
  if (tid < 16) {
    int r = tid;
    float m = logit_s[r * 12];
#pragma unroll
    for (int k = 1; k < 10; ++k) m = fmaxf(m, logit_s[r * 12 + k]);
    float s = 0.f;
#pragma unroll
    for (int k = 0; k < 10; ++k)
      s += __builtin_amdgcn_exp2f(L2E * (logit_s[r * 12 + k] - m));
    float ls = __builtin_amdgcn_logf(s) * 0.6931471805599453f;
#pragma unroll
    for (int k = 0; k < 10; ++k)
      out[(r0 + r) * 10 + k] = logit_s[r * 12 + k] - m - ls;
  }
}

extern "C" void kernel_launch(void* const* d_in, const int* in_sizes, int n_in,
                              void* d_out, int out_size, void* d_ws, size_t ws_size,
                              hipStream_t stream) {
  const float* x     = (const float*)d_in[0];
  const float* h0    = (const float*)d_in[1];
  const float* c0    = (const float*)d_in[2];
  const float* W_ih  = (const float*)d_in[3];
  const float* W_hh  = (const float*)d_in[4];
  const float* b_ih  = (const float*)d_in[5];
  const float* b_hh  = (const float*)d_in[6];
  const float* fc1_w = (const float*)d_in[7];
  const float* fc1_b = (const float*)d_in[8];
  const float* fc2_w = (const float*)d_in[9];
  const float* fc2_b = (const float*)d_in[10];
  float* out = (float*)d_out;
  unsigned char* ws = (unsigned char*)d_ws;

  prep_all<<<1032, 256, 0, stream>>>(W_ih, W_hh, b_ih, b_hh, fc1_w, fc1_b, ws);
  lstm_fused<<<256, 768, 0, stream>>>(x, h0, c0, fc2_w, fc2_b, ws, out);
}

// Round 6
// 182.157 us; speedup vs baseline: 5.7609x; 1.6300x over previous
//
#include <hip/hip_runtime.h>

// Problem constants
#define T_LEN 120
#define H 128
#define FC1_STRIDE 15360 // T*H

// workspace layout (bytes)
#define OFF_WHH   0u        // [512][128] bf16, pre-scaled by gate constant
#define OFF_WXB   131072u   // [512][32]  bf16 (W_ih cols 0-3, bias col 4), pre-scaled
#define OFF_FC1W  163840u   // [128][15360] bf16 (rows >=100 zero)
#define OFF_FC1B  4096000u  // [128] f32 (zero-padded)

typedef short short8 __attribute__((ext_vector_type(8)));   // 8 bf16 in 4 VGPRs
typedef float f32x4 __attribute__((ext_vector_type(4)));
typedef unsigned int ui32x4 __attribute__((ext_vector_type(4)));

#define L2E 1.4426950408889634f
#define SWZ(r) (((((r) & 7) ^ (((r) >> 3) << 1))) << 4)
#define MFMA __builtin_amdgcn_mfma_f32_16x16x32_bf16
#define BAR() do { asm volatile("s_waitcnt lgkmcnt(0)" ::: "memory"); \
                   __builtin_amdgcn_s_barrier(); \
                   asm volatile("" ::: "memory"); } while (0)

__device__ __forceinline__ unsigned short f2bu(float f) {   // f32 -> bf16 (RNE)
  unsigned u = __builtin_bit_cast(unsigned, f);
  u += 0x7fffu + ((u >> 16) & 1u);
  return (unsigned short)(u >> 16);
}
__device__ __forceinline__ float gate_scale(int row) {
  // rows 0-127: i, 128-255: f, 256-383: g, 384-511: o
  return ((row >> 7) == 2) ? 2.0f * L2E : -L2E;
}

// ---- one-time weight conversion (single launch) ----
__global__ void prep_all(const float* __restrict__ W_ih, const float* __restrict__ W_hh,
                         const float* __restrict__ b_ih, const float* __restrict__ b_hh,
                         const float* __restrict__ fc1_w, const float* __restrict__ fc1_b,
                         unsigned char* __restrict__ ws) {
  if (blockIdx.x < 1024) {
    unsigned short* w = (unsigned short*)(ws + OFF_FC1W);
    int j = blockIdx.x >> 3;
    int c0 = ((blockIdx.x & 7) * 256 + threadIdx.x) * 8;
    if (c0 >= FC1_STRIDE) return;
    short8 v = {0, 0, 0, 0, 0, 0, 0, 0};
    if (j < 100) {
      const float* src = fc1_w + j * FC1_STRIDE + c0;
#pragma unroll
      for (int e = 0; e < 8; ++e) ((unsigned short*)&v)[e] = f2bu(src[e]);
    }
    *(short8*)(w + j * FC1_STRIDE + c0) = v;
  } else {
    unsigned short* whh = (unsigned short*)(ws + OFF_WHH);
    unsigned short* wxb = (unsigned short*)(ws + OFF_WXB);
    float* fb = (float*)(ws + OFF_FC1B);
    int tid = (blockIdx.x - 1024) * 256 + threadIdx.x;
    const int nt = 8 * 256;
    for (int i = tid; i < 512 * 128; i += nt) {
      int row = i >> 7;
      whh[i] = f2bu(W_hh[i] * gate_scale(row));
    }
    for (int i = tid; i < 512 * 32; i += nt) {
      int j = i >> 5, k = i & 31;
      float s = gate_scale(j);
      float v = 0.f;
      if (k < 4) v = W_ih[j * 4 + k] * s;
      else if (k == 4) v = (b_ih[j] + b_hh[j]) * s;
      wxb[i] = f2bu(v);
    }
    for (int i = tid; i < 128; i += nt) fb[i] = (i < 100) ? fc1_b[i] : 0.f;
  }
}

// ---- fused persistent kernel: 256 blocks x 512 threads, 2 waves/SIMD ----
// Block owns 16 batch rows as TWO independent 8-row groups (A: rows 0-7,
// B: rows 8-15). Each group has its own M=16 MFMA tile (real tile rows
// {lq*4+q, q<2}), h_lds double-buffer, c-state and x-frags. Weights are
// shared. Two independent recurrence chains per wave -> ILP fills the
// dependency stalls that made R2 75% idle. Registers stay in the proven
// no-spill 2-wave/SIMD regime.
__global__ __launch_bounds__(512, 2)
void lstm_fused(const float* __restrict__ x, const float* __restrict__ h0,
                const float* __restrict__ c0, const float* __restrict__ fc2_w,
                const float* __restrict__ fc2_b, const unsigned char* __restrict__ ws,
                float* __restrict__ out) {
  __shared__ __align__(16) unsigned char xab[2 * T_LEN * 128]; // [grp][t][8 rows x 16B]; reused as hid[16][132] f32
  __shared__ __align__(16) unsigned char h_lds[2 * 2 * 4096];  // [grp][buf][16 rows x 256B], swizzled
  __shared__ __align__(16) float fc2w_s[1000];
  __shared__ float fc2b_s[10];
  __shared__ float logit_s[16 * 12];

  const int tid = threadIdx.x;
  const int w = tid >> 6;
  const int l = tid & 63;
  const int lq = l >> 4;
  const int lc = l & 15;
  const int r0 = blockIdx.x * 16;
  const int hcol = w * 16 + lc;

  const unsigned short* Whh = (const unsigned short*)(ws + OFF_WHH);
  const unsigned short* Wxb = (const unsigned short*)(ws + OFF_WXB);
  const unsigned short* FC1 = (const unsigned short*)(ws + OFF_FC1W);
  const float* FC1B = (const float*)(ws + OFF_FC1B);

  // stage fc2 weights
  for (int i = tid; i < 1000; i += 512) fc2w_s[i] = fc2_w[i];
  if (tid < 10) fc2b_s[tid] = fc2_b[tid];

  // zero the DUMMY tile rows ((r&3)>=2) of all 4 h buffers (disjoint from h0 writes)
  for (int i = tid; i < 2048; i += 512) {
    int gb = i >> 9;             // group*2+buf
    int rem = i & 511;
    int dr = rem >> 6;           // dummy row ordinal 0..7
    int word = rem & 63;
    int tr = ((dr >> 1) << 2) + 2 + (dr & 1);   // rows {2,3,6,7,10,11,14,15}
    *(unsigned*)(h_lds + gb * 4096 + tr * 256 + word * 4) = 0u;
  }
  // pack x A-frags: [grp][t][8 rows x 16B] = {x0,x1,x2,x3,1.0,0,0,0} bf16
  for (int i = tid; i < 2 * T_LEN * 8; i += 512) {
    int g = i / (T_LEN * 8);
    int rem = i - g * (T_LEN * 8);
    int t = rem >> 3, j = rem & 7;
    f32x4 xv = *(const f32x4*)(x + (r0 + g * 8 + j) * (T_LEN * 4) + t * 4);
    unsigned w0 = (unsigned)f2bu(xv[0]) | ((unsigned)f2bu(xv[1]) << 16);
    unsigned w1 = (unsigned)f2bu(xv[2]) | ((unsigned)f2bu(xv[3]) << 16);
    ui32x4 pk = {w0, w1, 0x3f80u, 0u};
    *(ui32x4*)(xab + g * (T_LEN * 128) + t * 128 + j * 16) = pk;
  }
  // stage h0 -> buffer 1 of each group; real row j -> tile row (j>>1)*4 + (j&1)
  for (int i = tid; i < 1024; i += 512) {
    int e = i * 2;
    int g = e >> 10, j = (e >> 7) & 7, c = e & 127;
    int tr = ((j >> 1) << 2) + (j & 1);
    const float* hp = h0 + (r0 + g * 8 + j) * H + c;
    unsigned u = (unsigned)f2bu(hp[0]) | ((unsigned)f2bu(hp[1]) << 16);
    *(unsigned*)(h_lds + g * 8192 + 4096 + tr * 256 + ((2 * c) ^ SWZ(tr))) = u;
  }
  // c0: lane owns real rows lq*2+q (q<2) per group
  float cA[2], cB[2];
#pragma unroll
  for (int q = 0; q < 2; ++q) {
    cA[q] = c0[(r0 + lq * 2 + q) * H + hcol];
    cB[q] = c0[(r0 + 8 + lq * 2 + q) * H + hcol];
  }

  // register-resident B fragments (shared by both groups)
  short8 bhh[4][4], bxb[4];
#pragma unroll
  for (int g = 0; g < 4; ++g) {
    int n0 = (g * 8 + w) * 16;
#pragma unroll
    for (int kk = 0; kk < 4; ++kk)
      bhh[g][kk] = *(const short8*)(Whh + (n0 + lc) * H + kk * 32 + lq * 8);
    bxb[g] = *(const short8*)(Wxb + (n0 + lc) * 32 + lq * 8);
  }
  const unsigned short* fc1row = FC1 + (w * 16 + lc) * FC1_STRIDE;
  f32x4 faccA = {0.f, 0.f, 0.f, 0.f}, faccB = {0.f, 0.f, 0.f, 0.f};

  __syncthreads();

  // initial A fragments from h0 (buffer 1 of each group)
  short8 haA[4], haB[4];
#pragma unroll
  for (int kk = 0; kk < 4; ++kk) {
    int off = lc * 256 + ((kk * 64 + lq * 16) ^ SWZ(lc));
    haA[kk] = *(const short8*)(h_lds + 4096 + off);
    haB[kk] = *(const short8*)(h_lds + 8192 + 4096 + off);
  }
  // xa: A-tile row lc duplicates a real row for dummies (harmless); only lq==0 matters
  const int jr = ((((lc >> 2) << 1) | (lc & 1))) & 7;
  short8 xaA = *(const short8*)(xab + jr * 16);
  short8 xaB = *(const short8*)(xab + T_LEN * 128 + jr * 16);

  const f32x4 zero4 = {0.f, 0.f, 0.f, 0.f};

  for (int t = 0; t < T_LEN; ++t) {
    // fc1 B-frags for slice t (in flight across the barrier on vmcnt)
    const unsigned short* fp = fc1row + t * 128 + lq * 8;
    short8 fb0 = *(const short8*)(fp + 0);
    short8 fb1 = *(const short8*)(fp + 32);
    short8 fb2 = *(const short8*)(fp + 64);
    short8 fb3 = *(const short8*)(fp + 96);

    // two independent gate chains, interleaved in source
    f32x4 a0 = MFMA(xaA, bxb[0], zero4, 0, 0, 0);
    f32x4 b0 = MFMA(xaB, bxb[0], zero4, 0, 0, 0);
    f32x4 a1 = MFMA(xaA, bxb[1], zero4, 0, 0, 0);
    f32x4 b1 = MFMA(xaB, bxb[1], zero4, 0, 0, 0);
    f32x4 a2 = MFMA(xaA, bxb[2], zero4, 0, 0, 0);
    f32x4 b2 = MFMA(xaB, bxb[2], zero4, 0, 0, 0);
    f32x4 a3 = MFMA(xaA, bxb[3], zero4, 0, 0, 0);
    f32x4 b3 = MFMA(xaB, bxb[3], zero4, 0, 0, 0);
#pragma unroll
    for (int kk = 0; kk < 4; ++kk) {
      a0 = MFMA(haA[kk], bhh[0][kk], a0, 0, 0, 0);
      b0 = MFMA(haB[kk], bhh[0][kk], b0, 0, 0, 0);
      a1 = MFMA(haA[kk], bhh[1][kk], a1, 0, 0, 0);
      b1 = MFMA(haB[kk], bhh[1][kk], b1, 0, 0, 0);
      a2 = MFMA(haA[kk], bhh[2][kk], a2, 0, 0, 0);
      b2 = MFMA(haB[kk], bhh[2][kk], b2, 0, 0, 0);
      a3 = MFMA(haA[kk], bhh[3][kk], a3, 0, 0, 0);
      b3 = MFMA(haB[kk], bhh[3][kk], b3, 0, 0, 0);
    }

    // activations + state update + h store, groups interleaved (4 indep chains)
    unsigned char* hwA = h_lds + (t & 1) * 4096;
    unsigned char* hwB = h_lds + 8192 + (t & 1) * 4096;
#pragma unroll
    for (int q = 0; q < 2; ++q) {
      int r = lq * 4 + q;
      unsigned soff = (unsigned)(r * 256 + ((2 * hcol) ^ SWZ(r)));
      {
        float ea = __builtin_amdgcn_exp2f(a0[q]);
        float eb = __builtin_amdgcn_exp2f(a1[q]);
        float ec = __builtin_amdgcn_exp2f(a2[q]);
        float ed = __builtin_amdgcn_exp2f(a3[q]);
        float a = 1.f + ea, b = 1.f + eb, d = 1.f + ec, e1 = 1.f + ed;
        float rab = __builtin_amdgcn_rcpf(a * b);
        float rde = __builtin_amdgcn_rcpf(d * e1);
        float cn = (a * rab) * cA[q] + (b * rab) * (1.f - 2.f * (e1 * rde));
        cA[q] = cn;
        float et = __builtin_amdgcn_exp2f(2.8853900817779268f * cn);
        float hv = (d * rde) * (1.f - 2.f * __builtin_amdgcn_rcpf(1.f + et));
        *(unsigned short*)(hwA + soff) = f2bu(hv);
      }
      {
        float ea = __builtin_amdgcn_exp2f(b0[q]);
        float eb = __builtin_amdgcn_exp2f(b1[q]);
        float ec = __builtin_amdgcn_exp2f(b2[q]);
        float ed = __builtin_amdgcn_exp2f(b3[q]);
        float a = 1.f + ea, b = 1.f + eb, d = 1.f + ec, e1 = 1.f + ed;
        float rab = __builtin_amdgcn_rcpf(a * b);
        float rde = __builtin_amdgcn_rcpf(d * e1);
        float cn = (a * rab) * cB[q] + (b * rab) * (1.f - 2.f * (e1 * rde));
        cB[q] = cn;
        float et = __builtin_amdgcn_exp2f(2.8853900817779268f * cn);
        float hv = (d * rde) * (1.f - 2.f * __builtin_amdgcn_rcpf(1.f + et));
        *(unsigned short*)(hwB + soff) = f2bu(hv);
      }
    }

    BAR();   // h_t complete in both groups

    // reload h_t fragments; next xa; fc1 partials (off next step's chain head)
#pragma unroll
    for (int kk = 0; kk < 4; ++kk) {
      int off = lc * 256 + ((kk * 64 + lq * 16) ^ SWZ(lc));
      haA[kk] = *(const short8*)(hwA + off);
      haB[kk] = *(const short8*)(hwB + off);
    }
    int tn = (t + 1 < T_LEN) ? t + 1 : t;
    xaA = *(const short8*)(xab + tn * 128 + jr * 16);
    xaB = *(const short8*)(xab + T_LEN * 128 + tn * 128 + jr * 16);

    faccA = MFMA(haA[0], fb0, faccA, 0, 0, 0);
    faccB = MFMA(haB[0], fb0, faccB, 0, 0, 0);
    faccA = MFMA(haA[1], fb1, faccA, 0, 0, 0);
    faccB = MFMA(haB[1], fb1, faccB, 0, 0, 0);
    faccA = MFMA(haA[2], fb2, faccA, 0, 0, 0);
    faccB = MFMA(haB[2], fb2, faccB, 0, 0, 0);
    faccA = MFMA(haA[3], fb3, faccA, 0, 0, 0);
    faccB = MFMA(haB[3], fb3, faccB, 0, 0, 0);
  }

  // ---- epilogue: bias+ReLU -> fc2 -> log_softmax ----
  float bias = FC1B[hcol];
  __syncthreads();                 // everyone out of the loop; xab free
  float* hid = (float*)xab;        // [16][132] padded
#pragma unroll
  for (int q = 0; q < 2; ++q) {
    float vA = faccA[q] + bias;
    float vB = faccB[q] + bias;
    hid[(lq * 2 + q) * 132 + hcol] = vA > 0.f ? vA : 0.f;
    hid[(8 + lq * 2 + q) * 132 + hcol] = vB > 0.f ? vB : 0.f;
  }
  __syncthreads();
  if (tid < 160) {
    int r = tid & 15, k = tid >> 4;
    float a = fc2b_s[k];
#pragma unroll 4
    for (int j = 0; j < 100; ++j) a += hid[r * 132 + j] * fc2w_s[k * 100 + j];
    logit_s[r * 12 + k] = a;
  }
  __syncthreads();
  if (tid < 16) {
    int r = tid;
    float m = logit_s[r * 12];
#pragma unroll
    for (int k = 1; k < 10; ++k) m = fmaxf(m, logit_s[r * 12 + k]);
    float s = 0.f;
#pragma unroll
    for (int k = 0; k < 10; ++k)
      s += __builtin_amdgcn_exp2f(L2E * (logit_s[r * 12 + k] - m));
    float ls = __builtin_amdgcn_logf(s) * 0.6931471805599453f;
#pragma unroll
    for (int k = 0; k < 10; ++k)
      out[(r0 + r) * 10 + k] = logit_s[r * 12 + k] - m - ls;
  }
}

extern "C" void kernel_launch(void* const* d_in, const int* in_sizes, int n_in,
                              void* d_out, int out_size, void* d_ws, size_t ws_size,
                              hipStream_t stream) {
  const float* x     = (const float*)d_in[0];
  const float* h0    = (const float*)d_in[1];
  const float* c0    = (const float*)d_in[2];
  const float* W_ih  = (const float*)d_in[3];
  const float* W_hh  = (const float*)d_in[4];
  const float* b_ih  = (const float*)d_in[5];
  const float* b_hh  = (const float*)d_in[6];
  const float* fc1_w = (const float*)d_in[7];
  const float* fc1_b = (const float*)d_in[8];
  const float* fc2_w = (const float*)d_in[9];
  const float* fc2_b = (const float*)d_in[10];
  float* out = (float*)d_out;
  unsigned char* ws = (unsigned char*)d_ws;

  prep_all<<<1032, 256, 0, stream>>>(W_ih, W_hh, b_ih, b_hh, fc1_w, fc1_b, ws);
  lstm_fused<<<256, 512, 0, stream>>>(x, h0, c0, fc2_w, fc2_b, ws, out);
}

// Round 7
// 147.193 us; speedup vs baseline: 7.1293x; 1.2375x over previous
//
#include <hip/hip_runtime.h>

// Problem constants
#define T_LEN 120
#define H 128
#define ROWS 16          // batch rows per block
#define FC1_STRIDE 15360 // T*H

// workspace layout (bytes)
#define OFF_WHH   0u        // [512][128] bf16, pre-scaled by gate constant
#define OFF_WXB   131072u   // [512][32]  bf16 (W_ih cols 0-3, bias col 4), pre-scaled
#define OFF_FC1W  163840u   // [128][15360] bf16 (rows >=100 zero)
#define OFF_FC1B  4096000u  // [128] f32 (zero-padded)

typedef short short8 __attribute__((ext_vector_type(8)));   // 8 bf16 in 4 VGPRs
typedef float f32x4 __attribute__((ext_vector_type(4)));
typedef unsigned int ui32x4 __attribute__((ext_vector_type(4)));

#define L2E 1.4426950408889634f
#define SWZ(r) (((((r) & 7) ^ (((r) >> 3) << 1))) << 4)
#define MFMA __builtin_amdgcn_mfma_f32_16x16x32_bf16
#define BAR() do { asm volatile("s_waitcnt lgkmcnt(0)" ::: "memory"); \
                   __builtin_amdgcn_s_barrier(); \
                   asm volatile("" ::: "memory"); } while (0)

__device__ __forceinline__ unsigned short f2bu(float f) {   // f32 -> bf16 (RNE)
  unsigned u = __builtin_bit_cast(unsigned, f);
  u += 0x7fffu + ((u >> 16) & 1u);
  return (unsigned short)(u >> 16);
}
__device__ __forceinline__ float gate_scale(int row) {
  // rows 0-127: i, 128-255: f, 256-383: g, 384-511: o
  return ((row >> 7) == 2) ? 2.0f * L2E : -L2E;
}

// ---- one-time weight conversion (single launch) ----
__global__ void prep_all(const float* __restrict__ W_ih, const float* __restrict__ W_hh,
                         const float* __restrict__ b_ih, const float* __restrict__ b_hh,
                         const float* __restrict__ fc1_w, const float* __restrict__ fc1_b,
                         unsigned char* __restrict__ ws) {
  if (blockIdx.x < 1024) {
    unsigned short* w = (unsigned short*)(ws + OFF_FC1W);
    int j = blockIdx.x >> 3;
    int c0 = ((blockIdx.x & 7) * 256 + threadIdx.x) * 8;
    if (c0 >= FC1_STRIDE) return;
    short8 v = {0, 0, 0, 0, 0, 0, 0, 0};
    if (j < 100) {
      const float* src = fc1_w + j * FC1_STRIDE + c0;
#pragma unroll
      for (int e = 0; e < 8; ++e) ((unsigned short*)&v)[e] = f2bu(src[e]);
    }
    *(short8*)(w + j * FC1_STRIDE + c0) = v;
  } else {
    unsigned short* whh = (unsigned short*)(ws + OFF_WHH);
    unsigned short* wxb = (unsigned short*)(ws + OFF_WXB);
    float* fb = (float*)(ws + OFF_FC1B);
    int tid = (blockIdx.x - 1024) * 256 + threadIdx.x;
    const int nt = 8 * 256;
    for (int i = tid; i < 512 * 128; i += nt) {
      int row = i >> 7;
      whh[i] = f2bu(W_hh[i] * gate_scale(row));
    }
    for (int i = tid; i < 512 * 32; i += nt) {
      int j = i >> 5, k = i & 31;
      float s = gate_scale(j);
      float v = 0.f;
      if (k < 4) v = W_ih[j * 4 + k] * s;
      else if (k == 4) v = (b_ih[j] + b_hh[j]) * s;
      wxb[i] = f2bu(v);
    }
    for (int i = tid; i < 128; i += nt) fb[i] = (i < 100) ? fc1_b[i] : 0.f;
  }
}

// ---- fused persistent kernel: 256 blocks x 512 threads (R2 structure + trims) ----
__global__ __launch_bounds__(512, 2)
void lstm_fused(const float* __restrict__ x, const float* __restrict__ h0,
                const float* __restrict__ c0, const float* __restrict__ fc2_w,
                const float* __restrict__ fc2_b, const unsigned char* __restrict__ ws,
                float* __restrict__ out) {
  __shared__ __align__(16) unsigned char xab[T_LEN * 256];      // packed x A-frags; reused as hid[16][132] f32
  __shared__ __align__(16) unsigned char h_lds[2 * 4096];       // double-buffered bf16 h (16 rows x 256B, swizzled)
  __shared__ __align__(16) float fc2w_s[1000];
  __shared__ float fc2b_s[10];
  __shared__ float logit_s[ROWS * 12];

  const int tid = threadIdx.x;
  const int w = tid >> 6;
  const int l = tid & 63;
  const int lq = l >> 4;
  const int lc = l & 15;
  const int r0 = blockIdx.x * ROWS;
  const int hcol = w * 16 + lc;

  const unsigned short* Whh = (const unsigned short*)(ws + OFF_WHH);
  const unsigned short* Wxb = (const unsigned short*)(ws + OFF_WXB);
  const unsigned short* FC1 = (const unsigned short*)(ws + OFF_FC1W);
  const float* FC1B = (const float*)(ws + OFF_FC1B);

  // stage fc2 weights
  for (int i = tid; i < 1000; i += 512) fc2w_s[i] = fc2_w[i];
  if (tid < 10) fc2b_s[tid] = fc2_b[tid];

  // pre-pack x A-frags for all t: slot (t,row) = 16B {x0,x1,x2,x3,1.0,0,0,0} bf16
  for (int i = tid; i < ROWS * T_LEN; i += 512) {
    int rr = i / T_LEN, t = i - rr * T_LEN;
    f32x4 xv = *(const f32x4*)(x + (r0 + rr) * (T_LEN * 4) + t * 4);
    unsigned w0 = (unsigned)f2bu(xv[0]) | ((unsigned)f2bu(xv[1]) << 16);
    unsigned w1 = (unsigned)f2bu(xv[2]) | ((unsigned)f2bu(xv[3]) << 16);
    ui32x4 pk = {w0, w1, 0x3f80u, 0u};
    *(ui32x4*)(xab + t * 256 + rr * 16) = pk;
  }
  // stage h0 -> buffer 1 (loop t=0 writes buffer 0)
  for (int e = tid * 2; e < ROWS * H; e += 1024) {
    int r = e >> 7, c = e & 127;
    unsigned u = (unsigned)f2bu(h0[(r0 + r) * H + c]) |
                 ((unsigned)f2bu(h0[(r0 + r) * H + c + 1]) << 16);
    *(unsigned*)(h_lds + 4096 + r * 256 + ((2 * c) ^ SWZ(r))) = u;
  }
  // c0: lane owns rows lq*4+q, col hcol
  float c_reg[4];
#pragma unroll
  for (int q = 0; q < 4; ++q) c_reg[q] = c0[(r0 + lq * 4 + q) * H + hcol];

  // register-resident B fragments; wave w owns gate tiles {w, 8+w, 16+w, 24+w}
  short8 bhh[4][4], bxb[4];
#pragma unroll
  for (int g = 0; g < 4; ++g) {
    int n0 = (g * 8 + w) * 16;
#pragma unroll
    for (int kk = 0; kk < 4; ++kk)
      bhh[g][kk] = *(const short8*)(Whh + (n0 + lc) * H + kk * 32 + lq * 8);
    bxb[g] = *(const short8*)(Wxb + (n0 + lc) * 32 + lq * 8);
  }
  const unsigned short* fc1row = FC1 + (w * 16 + lc) * FC1_STRIDE;
  f32x4 facc = {0.f, 0.f, 0.f, 0.f};

  __syncthreads();

  // initial A fragments (h0, buffer 1) + xa(t=0) + accX(t=0)
  short8 ha[4];
#pragma unroll
  for (int kk = 0; kk < 4; ++kk)
    ha[kk] = *(const short8*)(h_lds + 4096 + lc * 256 + ((kk * 64 + lq * 16) ^ SWZ(lc)));
  short8 xa = *(const short8*)(xab + lc * 16);

  const f32x4 zero4 = {0.f, 0.f, 0.f, 0.f};
  f32x4 accX0 = MFMA(xa, bxb[0], zero4, 0, 0, 0);
  f32x4 accX1 = MFMA(xa, bxb[1], zero4, 0, 0, 0);
  f32x4 accX2 = MFMA(xa, bxb[2], zero4, 0, 0, 0);
  f32x4 accX3 = MFMA(xa, bxb[3], zero4, 0, 0, 0);

  for (int t = 0; t < T_LEN; ++t) {
    // --- critical section: gates + activations (favored by setprio) ---
    __builtin_amdgcn_s_setprio(1);
    f32x4 acc0 = accX0, acc1 = accX1, acc2 = accX2, acc3 = accX3;
#pragma unroll
    for (int kk = 0; kk < 4; ++kk) {
      acc0 = MFMA(ha[kk], bhh[0][kk], acc0, 0, 0, 0);
      acc1 = MFMA(ha[kk], bhh[1][kk], acc1, 0, 0, 0);
      acc2 = MFMA(ha[kk], bhh[2][kk], acc2, 0, 0, 0);
      acc3 = MFMA(ha[kk], bhh[3][kk], acc3, 0, 0, 0);
    }

    // fc1 B-frags for slice t: issue now (consumed post-barrier, ~1000cy later)
    const unsigned short* fp = fc1row + t * 128 + lq * 8;
    short8 fb0 = *(const short8*)(fp + 0);
    short8 fb1 = *(const short8*)(fp + 32);
    short8 fb2 = *(const short8*)(fp + 64);
    short8 fb3 = *(const short8*)(fp + 96);
    // next xa (LDS broadcast read; consumed in the post-store tail)
    int tn = (t + 1 < T_LEN) ? t + 1 : t;
    short8 xan = *(const short8*)(xab + tn * 256 + lc * 16);

    // activations: q-pair rcp batching (26 trans/lane vs 32), store ASAP
    unsigned char* hw = h_lds + (t & 1) * 4096;
#pragma unroll
    for (int qp = 0; qp < 2; ++qp) {
      const int q0 = qp * 2, q1 = q0 + 1;
      float ea0 = __builtin_amdgcn_exp2f(acc0[q0]), ea1 = __builtin_amdgcn_exp2f(acc0[q1]);
      float eb0 = __builtin_amdgcn_exp2f(acc1[q0]), eb1 = __builtin_amdgcn_exp2f(acc1[q1]);
      float ec0 = __builtin_amdgcn_exp2f(acc2[q0]), ec1 = __builtin_amdgcn_exp2f(acc2[q1]);
      float ed0 = __builtin_amdgcn_exp2f(acc3[q0]), ed1 = __builtin_amdgcn_exp2f(acc3[q1]);
      float a0 = 1.f + ea0, b0 = 1.f + eb0, d0 = 1.f + ec0, e0 = 1.f + ed0;
      float a1 = 1.f + ea1, b1 = 1.f + eb1, d1 = 1.f + ec1, e1 = 1.f + ed1;
      float ab0 = a0 * b0, ab1 = a1 * b1, de0 = d0 * e0, de1 = d1 * e1;
      float rAB = __builtin_amdgcn_rcpf(ab0 * ab1);
      float rDE = __builtin_amdgcn_rcpf(de0 * de1);
      float rab0 = rAB * ab1, rab1 = rAB * ab0;
      float rde0 = rDE * de1, rde1 = rDE * de0;
      float iv0 = b0 * rab0, fv0 = a0 * rab0;
      float iv1 = b1 * rab1, fv1 = a1 * rab1;
      float gv0 = 1.f - 2.f * (e0 * rde0), ov0 = d0 * rde0;
      float gv1 = 1.f - 2.f * (e1 * rde1), ov1 = d1 * rde1;
      float cn0 = fv0 * c_reg[q0] + iv0 * gv0;
      float cn1 = fv1 * c_reg[q1] + iv1 * gv1;
      c_reg[q0] = cn0; c_reg[q1] = cn1;
      float et0 = __builtin_amdgcn_exp2f(2.8853900817779268f * cn0);
      float et1 = __builtin_amdgcn_exp2f(2.8853900817779268f * cn1);
      float t0 = 1.f + et0, t1 = 1.f + et1;
      float rT = __builtin_amdgcn_rcpf(t0 * t1);
      float hv0 = ov0 * (1.f - 2.f * (rT * t1));
      float hv1 = ov1 * (1.f - 2.f * (rT * t0));
      int r0r = lq * 4 + q0, r1r = lq * 4 + q1;
      *(unsigned short*)(hw + r0r * 256 + ((2 * hcol) ^ SWZ(r0r))) = f2bu(hv0);
      *(unsigned short*)(hw + r1r * 256 + ((2 * hcol) ^ SWZ(r1r))) = f2bu(hv1);
    }
    __builtin_amdgcn_s_setprio(0);

    // tail before barrier: precompute next step's x-part of gates
    accX0 = MFMA(xan, bxb[0], zero4, 0, 0, 0);
    accX1 = MFMA(xan, bxb[1], zero4, 0, 0, 0);
    accX2 = MFMA(xan, bxb[2], zero4, 0, 0, 0);
    accX3 = MFMA(xan, bxb[3], zero4, 0, 0, 0);

    BAR();   // h_t complete

    // read h_t fragments; fc1 partial (new h x this step's fb)
#pragma unroll
    for (int kk = 0; kk < 4; ++kk)
      ha[kk] = *(const short8*)(hw + lc * 256 + ((kk * 64 + lq * 16) ^ SWZ(lc)));
    facc = MFMA(ha[0], fb0, facc, 0, 0, 0);
    facc = MFMA(ha[1], fb1, facc, 0, 0, 0);
    facc = MFMA(ha[2], fb2, facc, 0, 0, 0);
    facc = MFMA(ha[3], fb3, facc, 0, 0, 0);
  }

  // ---- epilogue: bias+ReLU -> fc2 -> log_softmax ----
  float bias = FC1B[hcol];
  __syncthreads();                 // everyone out of the loop; xab free
  float* hid = (float*)xab;        // [16][132] padded
#pragma unroll
  for (int q = 0; q < 4; ++q) {
    float v = facc[q] + bias;
    hid[(lq * 4 + q) * 132 + hcol] = v > 0.f ? v : 0.f;
  }
  __syncthreads();
  if (tid < 160) {
    int r = tid & 15, k = tid >> 4;
    float a = fc2b_s[k];
#pragma unroll 4
    for (int j = 0; j < 100; ++j) a += hid[r * 132 + j] * fc2w_s[k * 100 + j];
    logit_s[r * 12 + k] = a;
  }
  __syncthreads();
  if (tid < 16) {
    int r = tid;
    float m = logit_s[r * 12];
#pragma unroll
    for (int k = 1; k < 10; ++k) m = fmaxf(m, logit_s[r * 12 + k]);
    float s = 0.f;
#pragma unroll
    for (int k = 0; k < 10; ++k)
      s += __builtin_amdgcn_exp2f(L2E * (logit_s[r * 12 + k] - m));
    float ls = __builtin_amdgcn_logf(s) * 0.6931471805599453f;
#pragma unroll
    for (int k = 0; k < 10; ++k)
      out[(r0 + r) * 10 + k] = logit_s[r * 12 + k] - m - ls;
  }
}

extern "C" void kernel_launch(void* const* d_in, const int* in_sizes, int n_in,
                              void* d_out, int out_size, void* d_ws, size_t ws_size,
                              hipStream_t stream) {
  const float* x     = (const float*)d_in[0];
  const float* h0    = (const float*)d_in[1];
  const float* c0    = (const float*)d_in[2];
  const float* W_ih  = (const float*)d_in[3];
  const float* W_hh  = (const float*)d_in[4];
  const float* b_ih  = (const float*)d_in[5];
  const float* b_hh  = (const float*)d_in[6];
  const float* fc1_w = (const float*)d_in[7];
  const float* fc1_b = (const float*)d_in[8];
  const float* fc2_w = (const float*)d_in[9];
  const float* fc2_b = (const float*)d_in[10];
  float* out = (float*)d_out;
  unsigned char* ws = (unsigned char*)d_ws;

  prep_all<<<1032, 256, 0, stream>>>(W_ih, W_hh, b_ih, b_hh, fc1_w, fc1_b, ws);
  lstm_fused<<<256, 512, 0, stream>>>(x, h0, c0, fc2_w, fc2_b, ws, out);
}

// Round 8
// 145.729 us; speedup vs baseline: 7.2010x; 1.0101x over previous
//
#include <hip/hip_runtime.h>

// Problem constants
#define T_LEN 120
#define H 128
#define ROWS 16          // batch rows per block
#define FC1_STRIDE 15360 // T*H

// workspace layout (bytes)
#define OFF_WHH   0u        // [512][128] bf16, pre-scaled by gate constant
#define OFF_WXB   131072u   // [512][32]  bf16 (W_ih cols 0-3, bias col 4), pre-scaled
#define OFF_FC1W  163840u   // [128][15360] bf16 (rows >=100 zero)
#define OFF_FC1B  4096000u  // [128] f32 (zero-padded)

typedef short short8 __attribute__((ext_vector_type(8)));   // 8 bf16 in 4 VGPRs
typedef float f32x4 __attribute__((ext_vector_type(4)));
typedef unsigned int ui32x4 __attribute__((ext_vector_type(4)));

#define L2E 1.4426950408889634f
#define SWZ(r) (((((r) & 7) ^ (((r) >> 3) << 1))) << 4)
#define MFMA __builtin_amdgcn_mfma_f32_16x16x32_bf16
#define BAR() do { asm volatile("s_waitcnt lgkmcnt(0)" ::: "memory"); \
                   __builtin_amdgcn_s_barrier(); \
                   asm volatile("" ::: "memory"); } while (0)

__device__ __forceinline__ unsigned short f2bu(float f) {   // f32 -> bf16 (RNE)
  unsigned u = __builtin_bit_cast(unsigned, f);
  u += 0x7fffu + ((u >> 16) & 1u);
  return (unsigned short)(u >> 16);
}
__device__ __forceinline__ unsigned cvt_pk_bf16(float lo, float hi) { // 2xf32 -> packed bf16 (RNE)
  unsigned r;
  asm("v_cvt_pk_bf16_f32 %0, %1, %2" : "=v"(r) : "v"(lo), "v"(hi));
  return r;
}
__device__ __forceinline__ float gate_scale(int row) {
  // rows 0-127: i, 128-255: f, 256-383: g, 384-511: o
  return ((row >> 7) == 2) ? 2.0f * L2E : -L2E;
}

// ---- one-time weight conversion (single launch) ----
__global__ void prep_all(const float* __restrict__ W_ih, const float* __restrict__ W_hh,
                         const float* __restrict__ b_ih, const float* __restrict__ b_hh,
                         const float* __restrict__ fc1_w, const float* __restrict__ fc1_b,
                         unsigned char* __restrict__ ws) {
  if (blockIdx.x < 1024) {
    unsigned short* w = (unsigned short*)(ws + OFF_FC1W);
    int j = blockIdx.x >> 3;
    int c0 = ((blockIdx.x & 7) * 256 + threadIdx.x) * 8;
    if (c0 >= FC1_STRIDE) return;
    short8 v = {0, 0, 0, 0, 0, 0, 0, 0};
    if (j < 100) {
      const float* src = fc1_w + j * FC1_STRIDE + c0;
#pragma unroll
      for (int e = 0; e < 8; ++e) ((unsigned short*)&v)[e] = f2bu(src[e]);
    }
    *(short8*)(w + j * FC1_STRIDE + c0) = v;
  } else {
    unsigned short* whh = (unsigned short*)(ws + OFF_WHH);
    unsigned short* wxb = (unsigned short*)(ws + OFF_WXB);
    float* fb = (float*)(ws + OFF_FC1B);
    int tid = (blockIdx.x - 1024) * 256 + threadIdx.x;
    const int nt = 8 * 256;
    for (int i = tid; i < 512 * 128; i += nt) {
      int row = i >> 7;
      whh[i] = f2bu(W_hh[i] * gate_scale(row));
    }
    for (int i = tid; i < 512 * 32; i += nt) {
      int j = i >> 5, k = i & 31;
      float s = gate_scale(j);
      float v = 0.f;
      if (k < 4) v = W_ih[j * 4 + k] * s;
      else if (k == 4) v = (b_ih[j] + b_hh[j]) * s;
      wxb[i] = f2bu(v);
    }
    for (int i = tid; i < 128; i += nt) fb[i] = (i < 100) ? fc1_b[i] : 0.f;
  }
}

// ---- fused persistent kernel: 256 blocks x 512 threads ----
__global__ __launch_bounds__(512, 2)
void lstm_fused(const float* __restrict__ x, const float* __restrict__ h0,
                const float* __restrict__ c0, const float* __restrict__ fc2_w,
                const float* __restrict__ fc2_b, const unsigned char* __restrict__ ws,
                float* __restrict__ out) {
  __shared__ __align__(16) unsigned char xab[T_LEN * 256];      // packed x A-frags; reused as hid[16][132] f32
  __shared__ __align__(16) unsigned char h_lds[2 * 4096];       // double-buffered bf16 h (16 rows x 256B, swizzled)
  __shared__ __align__(16) float fc2w_s[1000];
  __shared__ float fc2b_s[10];
  __shared__ float logit_s[ROWS * 12];

  const int tid = threadIdx.x;
  const int w = tid >> 6;
  const int l = tid & 63;
  const int lq = l >> 4;
  const int lc = l & 15;
  const int r0 = blockIdx.x * ROWS;
  const int hcol = w * 16 + lc;

  const unsigned short* Whh = (const unsigned short*)(ws + OFF_WHH);
  const unsigned short* Wxb = (const unsigned short*)(ws + OFF_WXB);
  const unsigned short* FC1 = (const unsigned short*)(ws + OFF_FC1W);
  const float* FC1B = (const float*)(ws + OFF_FC1B);

  // stage fc2 weights
  for (int i = tid; i < 1000; i += 512) fc2w_s[i] = fc2_w[i];
  if (tid < 10) fc2b_s[tid] = fc2_b[tid];

  // pre-pack x A-frags for all t: slot (t,row) = 16B {x0,x1,x2,x3,1.0,0,0,0} bf16
  for (int i = tid; i < ROWS * T_LEN; i += 512) {
    int rr = i / T_LEN, t = i - rr * T_LEN;
    f32x4 xv = *(const f32x4*)(x + (r0 + rr) * (T_LEN * 4) + t * 4);
    unsigned w0 = cvt_pk_bf16(xv[0], xv[1]);
    unsigned w1 = cvt_pk_bf16(xv[2], xv[3]);
    ui32x4 pk = {w0, w1, 0x3f80u, 0u};
    *(ui32x4*)(xab + t * 256 + rr * 16) = pk;
  }
  // stage h0 -> buffer 1 (loop t=0 writes buffer 0)
  for (int e = tid * 2; e < ROWS * H; e += 1024) {
    int r = e >> 7, c = e & 127;
    unsigned u = (unsigned)f2bu(h0[(r0 + r) * H + c]) |
                 ((unsigned)f2bu(h0[(r0 + r) * H + c + 1]) << 16);
    *(unsigned*)(h_lds + 4096 + r * 256 + ((2 * c) ^ SWZ(r))) = u;
  }
  // c0: lane owns rows lq*4+q, col hcol
  float c_reg[4];
#pragma unroll
  for (int q = 0; q < 4; ++q) c_reg[q] = c0[(r0 + lq * 4 + q) * H + hcol];

  // register-resident B fragments; wave w owns gate tiles {w, 8+w, 16+w, 24+w}
  short8 bhh[4][4], bxb[4];
#pragma unroll
  for (int g = 0; g < 4; ++g) {
    int n0 = (g * 8 + w) * 16;
#pragma unroll
    for (int kk = 0; kk < 4; ++kk)
      bhh[g][kk] = *(const short8*)(Whh + (n0 + lc) * H + kk * 32 + lq * 8);
    bxb[g] = *(const short8*)(Wxb + (n0 + lc) * 32 + lq * 8);
  }
  const unsigned short* fc1row = FC1 + (w * 16 + lc) * FC1_STRIDE;
  f32x4 facc = {0.f, 0.f, 0.f, 0.f};

  // precomputed swizzled h-store byte offsets for q=0..3 (both buffers share offset; base differs)
  unsigned soff[4];
#pragma unroll
  for (int q = 0; q < 4; ++q) {
    int r = lq * 4 + q;
    soff[q] = (unsigned)(r * 256 + ((2 * hcol) ^ SWZ(r)));
  }

  __syncthreads();

  // initial A fragments (h0, buffer 1) + xa(t=0) + accX(t=0)
  short8 ha[4];
#pragma unroll
  for (int kk = 0; kk < 4; ++kk)
    ha[kk] = *(const short8*)(h_lds + 4096 + lc * 256 + ((kk * 64 + lq * 16) ^ SWZ(lc)));
  short8 xa = *(const short8*)(xab + lc * 16);

  const f32x4 zero4 = {0.f, 0.f, 0.f, 0.f};
  f32x4 accX0 = MFMA(xa, bxb[0], zero4, 0, 0, 0);
  f32x4 accX1 = MFMA(xa, bxb[1], zero4, 0, 0, 0);
  f32x4 accX2 = MFMA(xa, bxb[2], zero4, 0, 0, 0);
  f32x4 accX3 = MFMA(xa, bxb[3], zero4, 0, 0, 0);

  // fc1 B-frags held one step behind (zero for t=0: adds h0*0 harmlessly? no --
  // fc1 pairs F_{t-1} with h_{t-1}; zero-init means the t=0 pre-barrier MFMA adds 0)
  short8 fbh0 = {0,0,0,0,0,0,0,0}, fbh1 = {0,0,0,0,0,0,0,0};
  short8 fbh2 = {0,0,0,0,0,0,0,0}, fbh3 = {0,0,0,0,0,0,0,0};

  for (int t = 0; t < T_LEN; ++t) {
    // --- critical section: gates (split chains, depth 3) + activations ---
    __builtin_amdgcn_s_setprio(1);
    f32x4 lo0 = accX0, lo1 = accX1, lo2 = accX2, lo3 = accX3;
    f32x4 hi0 = zero4, hi1 = zero4, hi2 = zero4, hi3 = zero4;
    lo0 = MFMA(ha[0], bhh[0][0], lo0, 0, 0, 0);
    lo1 = MFMA(ha[0], bhh[1][0], lo1, 0, 0, 0);
    lo2 = MFMA(ha[0], bhh[2][0], lo2, 0, 0, 0);
    lo3 = MFMA(ha[0], bhh[3][0], lo3, 0, 0, 0);
    hi0 = MFMA(ha[2], bhh[0][2], hi0, 0, 0, 0);
    hi1 = MFMA(ha[2], bhh[1][2], hi1, 0, 0, 0);
    hi2 = MFMA(ha[2], bhh[2][2], hi2, 0, 0, 0);
    hi3 = MFMA(ha[2], bhh[3][2], hi3, 0, 0, 0);
    lo0 = MFMA(ha[1], bhh[0][1], lo0, 0, 0, 0);
    lo1 = MFMA(ha[1], bhh[1][1], lo1, 0, 0, 0);
    lo2 = MFMA(ha[1], bhh[2][1], lo2, 0, 0, 0);
    lo3 = MFMA(ha[1], bhh[3][1], lo3, 0, 0, 0);
    hi0 = MFMA(ha[3], bhh[0][3], hi0, 0, 0, 0);
    hi1 = MFMA(ha[3], bhh[1][3], hi1, 0, 0, 0);
    hi2 = MFMA(ha[3], bhh[2][3], hi2, 0, 0, 0);
    hi3 = MFMA(ha[3], bhh[3][3], hi3, 0, 0, 0);

    // fc1 for slice t-1 with stale ha (= h_{t-1}): off the post-barrier chain,
    // fills the MFMA pipe while the VALU runs activations
    facc = MFMA(ha[0], fbh0, facc, 0, 0, 0);
    facc = MFMA(ha[1], fbh1, facc, 0, 0, 0);
    facc = MFMA(ha[2], fbh2, facc, 0, 0, 0);
    facc = MFMA(ha[3], fbh3, facc, 0, 0, 0);

    f32x4 acc0 = lo0 + hi0;
    f32x4 acc1 = lo1 + hi1;
    f32x4 acc2 = lo2 + hi2;
    f32x4 acc3 = lo3 + hi3;

    // fb for slice t (consumed next iteration pre-barrier; ~full step to land)
    const unsigned short* fp = fc1row + t * 128 + lq * 8;
    fbh0 = *(const short8*)(fp + 0);
    fbh1 = *(const short8*)(fp + 32);
    fbh2 = *(const short8*)(fp + 64);
    fbh3 = *(const short8*)(fp + 96);
    // next xa (LDS broadcast read; consumed in the post-store tail)
    int tn = (t + 1 < T_LEN) ? t + 1 : t;
    short8 xan = *(const short8*)(xab + tn * 256 + lc * 16);

    // activations: q-pair rcp batching (26 trans/lane), packed bf16 converts
    unsigned char* hw = h_lds + (t & 1) * 4096;
#pragma unroll
    for (int qp = 0; qp < 2; ++qp) {
      const int q0 = qp * 2, q1 = q0 + 1;
      float ea0 = __builtin_amdgcn_exp2f(acc0[q0]), ea1 = __builtin_amdgcn_exp2f(acc0[q1]);
      float eb0 = __builtin_amdgcn_exp2f(acc1[q0]), eb1 = __builtin_amdgcn_exp2f(acc1[q1]);
      float ec0 = __builtin_amdgcn_exp2f(acc2[q0]), ec1 = __builtin_amdgcn_exp2f(acc2[q1]);
      float ed0 = __builtin_amdgcn_exp2f(acc3[q0]), ed1 = __builtin_amdgcn_exp2f(acc3[q1]);
      float a0 = 1.f + ea0, b0 = 1.f + eb0, d0 = 1.f + ec0, e0 = 1.f + ed0;
      float a1 = 1.f + ea1, b1 = 1.f + eb1, d1 = 1.f + ec1, e1 = 1.f + ed1;
      float ab0 = a0 * b0, ab1 = a1 * b1, de0 = d0 * e0, de1 = d1 * e1;
      float rAB = __builtin_amdgcn_rcpf(ab0 * ab1);
      float rDE = __builtin_amdgcn_rcpf(de0 * de1);
      float rab0 = rAB * ab1, rab1 = rAB * ab0;
      float rde0 = rDE * de1, rde1 = rDE * de0;
      float iv0 = b0 * rab0, fv0 = a0 * rab0;
      float iv1 = b1 * rab1, fv1 = a1 * rab1;
      float gv0 = 1.f - 2.f * (e0 * rde0), ov0 = d0 * rde0;
      float gv1 = 1.f - 2.f * (e1 * rde1), ov1 = d1 * rde1;
      float cn0 = fv0 * c_reg[q0] + iv0 * gv0;
      float cn1 = fv1 * c_reg[q1] + iv1 * gv1;
      c_reg[q0] = cn0; c_reg[q1] = cn1;
      float et0 = __builtin_amdgcn_exp2f(2.8853900817779268f * cn0);
      float et1 = __builtin_amdgcn_exp2f(2.8853900817779268f * cn1);
      float t0 = 1.f + et0, t1 = 1.f + et1;
      float rT = __builtin_amdgcn_rcpf(t0 * t1);
      float hv0 = ov0 * (1.f - 2.f * (rT * t1));
      float hv1 = ov1 * (1.f - 2.f * (rT * t0));
      unsigned pk = cvt_pk_bf16(hv0, hv1);
      *(unsigned short*)(hw + soff[q0]) = (unsigned short)pk;
      *(unsigned short*)(hw + soff[q1]) = (unsigned short)(pk >> 16);
    }
    __builtin_amdgcn_s_setprio(0);

    // tail before barrier: precompute next step's x-part of gates
    accX0 = MFMA(xan, bxb[0], zero4, 0, 0, 0);
    accX1 = MFMA(xan, bxb[1], zero4, 0, 0, 0);
    accX2 = MFMA(xan, bxb[2], zero4, 0, 0, 0);
    accX3 = MFMA(xan, bxb[3], zero4, 0, 0, 0);

    BAR();   // h_t complete

    // read h_t fragments -> straight into next step's gate chains
#pragma unroll
    for (int kk = 0; kk < 4; ++kk)
      ha[kk] = *(const short8*)(hw + lc * 256 + ((kk * 64 + lq * 16) ^ SWZ(lc)));
  }
  // final fc1 term: F_119 with h_119 (ha holds h_119 after last barrier)
  facc = MFMA(ha[0], fbh0, facc, 0, 0, 0);
  facc = MFMA(ha[1], fbh1, facc, 0, 0, 0);
  facc = MFMA(ha[2], fbh2, facc, 0, 0, 0);
  facc = MFMA(ha[3], fbh3, facc, 0, 0, 0);

  // ---- epilogue: bias+ReLU -> fc2 -> log_softmax ----
  float bias = FC1B[hcol];
  __syncthreads();                 // everyone out of the loop; xab free
  float* hid = (float*)xab;        // [16][132] padded
#pragma unroll
  for (int q = 0; q < 4; ++q) {
    float v = facc[q] + bias;
    hid[(lq * 4 + q) * 132 + hcol] = v > 0.f ? v : 0.f;
  }
  __syncthreads();
  if (tid < 160) {
    int r = tid & 15, k = tid >> 4;
    float a = fc2b_s[k];
#pragma unroll 4
    for (int j = 0; j < 100; ++j) a += hid[r * 132 + j] * fc2w_s[k * 100 + j];
    logit_s[r * 12 + k] = a;
  }
  __syncthreads();
  if (tid < 16) {
    int r = tid;
    float m = logit_s[r * 12];
#pragma unroll
    for (int k = 1; k < 10; ++k) m = fmaxf(m, logit_s[r * 12 + k]);
    float s = 0.f;
#pragma unroll
    for (int k = 0; k < 10; ++k)
      s += __builtin_amdgcn_exp2f(L2E * (logit_s[r * 12 + k] - m));
    float ls = __builtin_amdgcn_logf(s) * 0.6931471805599453f;
#pragma unroll
    for (int k = 0; k < 10; ++k)
      out[(r0 + r) * 10 + k] = logit_s[r * 12 + k] - m - ls;
  }
}

extern "C" void kernel_launch(void* const* d_in, const int* in_sizes, int n_in,
                              void* d_out, int out_size, void* d_ws, size_t ws_size,
                              hipStream_t stream) {
  const float* x     = (const float*)d_in[0];
  const float* h0    = (const float*)d_in[1];
  const float* c0    = (const float*)d_in[2];
  const float* W_ih  = (const float*)d_in[3];
  const float* W_hh  = (const float*)d_in[4];
  const float* b_ih  = (const float*)d_in[5];
  const float* b_hh  = (const float*)d_in[6];
  const float* fc1_w = (const float*)d_in[7];
  const float* fc1_b = (const float*)d_in[8];
  const float* fc2_w = (const float*)d_in[9];
  const float* fc2_b = (const float*)d_in[10];
  float* out = (float*)d_out;
  unsigned char* ws = (unsigned char*)d_ws;

  prep_all<<<1032, 256, 0, stream>>>(W_ih, W_hh, b_ih, b_hh, fc1_w, fc1_b, ws);
  lstm_fused<<<256, 512, 0, stream>>>(x, h0, c0, fc2_w, fc2_b, ws, out);
}

// Round 9
// 141.143 us; speedup vs baseline: 7.4349x; 1.0325x over previous
//
#include <hip/hip_runtime.h>

// Problem constants
#define T_LEN 120
#define H 128
#define ROWS 16          // batch rows per block
#define FC1_STRIDE 15360 // T*H

// workspace layout (bytes)
#define OFF_WHH   0u        // [512][128] bf16, pre-scaled by gate constant
#define OFF_WXB   131072u   // [512][32]  bf16 (W_ih cols 0-3, bias col 4), pre-scaled
#define OFF_FC1W  163840u   // [128][15360] bf16 (rows >=100 zero)
#define OFF_FC1B  4096000u  // [128] f32 (zero-padded)

typedef short short8 __attribute__((ext_vector_type(8)));   // 8 bf16 in 4 VGPRs
typedef float f32x4 __attribute__((ext_vector_type(4)));
typedef unsigned int ui32x4 __attribute__((ext_vector_type(4)));

#define L2E 1.4426950408889634f
#define SWZ(r) (((((r) & 7) ^ (((r) >> 3) << 1))) << 4)
#define MFMA __builtin_amdgcn_mfma_f32_16x16x32_bf16
#define BAR() do { asm volatile("s_waitcnt lgkmcnt(0)" ::: "memory"); \
                   __builtin_amdgcn_s_barrier(); \
                   asm volatile("" ::: "memory"); } while (0)

__device__ __forceinline__ unsigned short f2bu(float f) {   // f32 -> bf16 (RNE)
  unsigned u = __builtin_bit_cast(unsigned, f);
  u += 0x7fffu + ((u >> 16) & 1u);
  return (unsigned short)(u >> 16);
}
__device__ __forceinline__ unsigned cvt_pk_bf16(float lo, float hi) { // 2xf32 -> packed bf16 (RNE)
  unsigned r;
  asm("v_cvt_pk_bf16_f32 %0, %1, %2" : "=v"(r) : "v"(lo), "v"(hi));
  return r;
}
__device__ __forceinline__ float gate_scale(int row) {
  // rows 0-127: i, 128-255: f, 256-383: g, 384-511: o
  return ((row >> 7) == 2) ? 2.0f * L2E : -L2E;
}

// ---- one-time weight conversion (single launch) ----
__global__ void prep_all(const float* __restrict__ W_ih, const float* __restrict__ W_hh,
                         const float* __restrict__ b_ih, const float* __restrict__ b_hh,
                         const float* __restrict__ fc1_w, const float* __restrict__ fc1_b,
                         unsigned char* __restrict__ ws) {
  if (blockIdx.x < 1024) {
    unsigned short* w = (unsigned short*)(ws + OFF_FC1W);
    int j = blockIdx.x >> 3;
    int c0 = ((blockIdx.x & 7) * 256 + threadIdx.x) * 8;
    if (c0 >= FC1_STRIDE) return;
    short8 v = {0, 0, 0, 0, 0, 0, 0, 0};
    if (j < 100) {
      const float* src = fc1_w + j * FC1_STRIDE + c0;
#pragma unroll
      for (int e = 0; e < 8; ++e) ((unsigned short*)&v)[e] = f2bu(src[e]);
    }
    *(short8*)(w + j * FC1_STRIDE + c0) = v;
  } else {
    unsigned short* whh = (unsigned short*)(ws + OFF_WHH);
    unsigned short* wxb = (unsigned short*)(ws + OFF_WXB);
    float* fb = (float*)(ws + OFF_FC1B);
    int tid = (blockIdx.x - 1024) * 256 + threadIdx.x;
    const int nt = 8 * 256;
    for (int i = tid; i < 512 * 128; i += nt) {
      int row = i >> 7;
      whh[i] = f2bu(W_hh[i] * gate_scale(row));
    }
    for (int i = tid; i < 512 * 32; i += nt) {
      int j = i >> 5, k = i & 31;
      float s = gate_scale(j);
      float v = 0.f;
      if (k < 4) v = W_ih[j * 4 + k] * s;
      else if (k == 4) v = (b_ih[j] + b_hh[j]) * s;
      wxb[i] = f2bu(v);
    }
    for (int i = tid; i < 128; i += nt) fb[i] = (i < 100) ? fc1_b[i] : 0.f;
  }
}

// ---- fused persistent kernel: 256 blocks x 512 threads ----
__global__ __launch_bounds__(512, 2)
void lstm_fused(const float* __restrict__ x, const float* __restrict__ h0,
                const float* __restrict__ c0, const float* __restrict__ fc2_w,
                const float* __restrict__ fc2_b, const unsigned char* __restrict__ ws,
                float* __restrict__ out) {
  __shared__ __align__(16) unsigned char xab[T_LEN * 256];      // packed x A-frags; reused as hid[16][132] f32
  __shared__ __align__(16) unsigned char h_lds[2 * 4096];       // double-buffered bf16 h (16 rows x 256B, swizzled)
  __shared__ __align__(16) float fc2w_s[1000];
  __shared__ float fc2b_s[10];
  __shared__ float logit_s[ROWS * 12];

  const int tid = threadIdx.x;
  const int w = tid >> 6;
  const int l = tid & 63;
  const int lq = l >> 4;
  const int lc = l & 15;
  const int r0 = blockIdx.x * ROWS;
  const int hcol = w * 16 + lc;

  const unsigned short* Whh = (const unsigned short*)(ws + OFF_WHH);
  const unsigned short* Wxb = (const unsigned short*)(ws + OFF_WXB);
  const unsigned short* FC1 = (const unsigned short*)(ws + OFF_FC1W);
  const float* FC1B = (const float*)(ws + OFF_FC1B);

  // stage fc2 weights
  for (int i = tid; i < 1000; i += 512) fc2w_s[i] = fc2_w[i];
  if (tid < 10) fc2b_s[tid] = fc2_b[tid];

  // pre-pack x A-frags for all t: slot (t,row) = 16B {x0,x1,x2,x3,1.0,0,0,0} bf16
  for (int i = tid; i < ROWS * T_LEN; i += 512) {
    int rr = i / T_LEN, t = i - rr * T_LEN;
    f32x4 xv = *(const f32x4*)(x + (r0 + rr) * (T_LEN * 4) + t * 4);
    unsigned w0 = cvt_pk_bf16(xv[0], xv[1]);
    unsigned w1 = cvt_pk_bf16(xv[2], xv[3]);
    ui32x4 pk = {w0, w1, 0x3f80u, 0u};
    *(ui32x4*)(xab + t * 256 + rr * 16) = pk;
  }
  // stage h0 -> buffer 1 (loop t=0 writes buffer 0)
  for (int e = tid * 2; e < ROWS * H; e += 1024) {
    int r = e >> 7, c = e & 127;
    unsigned u = (unsigned)f2bu(h0[(r0 + r) * H + c]) |
                 ((unsigned)f2bu(h0[(r0 + r) * H + c + 1]) << 16);
    *(unsigned*)(h_lds + 4096 + r * 256 + ((2 * c) ^ SWZ(r))) = u;
  }
  // c0: lane owns rows lq*4+q, col hcol
  float c_reg[4];
#pragma unroll
  for (int q = 0; q < 4; ++q) c_reg[q] = c0[(r0 + lq * 4 + q) * H + hcol];

  // register-resident B fragments; wave w owns gate tiles {w, 8+w, 16+w, 24+w}
  short8 bhh[4][4], bxb[4];
#pragma unroll
  for (int g = 0; g < 4; ++g) {
    int n0 = (g * 8 + w) * 16;
#pragma unroll
    for (int kk = 0; kk < 4; ++kk)
      bhh[g][kk] = *(const short8*)(Whh + (n0 + lc) * H + kk * 32 + lq * 8);
    bxb[g] = *(const short8*)(Wxb + (n0 + lc) * 32 + lq * 8);
  }
  const unsigned short* fc1row = FC1 + (w * 16 + lc) * FC1_STRIDE;
  f32x4 facc = {0.f, 0.f, 0.f, 0.f};

  // precomputed swizzled h-store byte offsets for q=0..3
  unsigned soff[4];
#pragma unroll
  for (int q = 0; q < 4; ++q) {
    int r = lq * 4 + q;
    soff[q] = (unsigned)(r * 256 + ((2 * hcol) ^ SWZ(r)));
  }

  __syncthreads();

  // initial A fragments (h0, buffer 1) + xa(t=0) + accX(t=0)
  short8 ha[4];
#pragma unroll
  for (int kk = 0; kk < 4; ++kk)
    ha[kk] = *(const short8*)(h_lds + 4096 + lc * 256 + ((kk * 64 + lq * 16) ^ SWZ(lc)));
  short8 xa = *(const short8*)(xab + lc * 16);

  const f32x4 zero4 = {0.f, 0.f, 0.f, 0.f};
  f32x4 accX0 = MFMA(xa, bxb[0], zero4, 0, 0, 0);
  f32x4 accX1 = MFMA(xa, bxb[1], zero4, 0, 0, 0);
  f32x4 accX2 = MFMA(xa, bxb[2], zero4, 0, 0, 0);
  f32x4 accX3 = MFMA(xa, bxb[3], zero4, 0, 0, 0);

  // fc1 B-frags held one step behind (zero for t=0: first pre-barrier fc1 MFMA adds 0)
  short8 fbh0 = {0,0,0,0,0,0,0,0}, fbh1 = {0,0,0,0,0,0,0,0};
  short8 fbh2 = {0,0,0,0,0,0,0,0}, fbh3 = {0,0,0,0,0,0,0,0};

#pragma unroll 2
  for (int t = 0; t < T_LEN; ++t) {
    // fb for slice t: issue VMEM first (independent; consumed next iteration)
    const unsigned short* fp = fc1row + t * 128 + lq * 8;
    short8 nfb0 = *(const short8*)(fp + 0);
    short8 nfb1 = *(const short8*)(fp + 32);
    short8 nfb2 = *(const short8*)(fp + 64);
    short8 nfb3 = *(const short8*)(fp + 96);

    // --- critical section: gates (split chains, depth 3) + activations ---
    __builtin_amdgcn_s_setprio(1);
    f32x4 lo0 = accX0, lo1 = accX1, lo2 = accX2, lo3 = accX3;
    f32x4 hi0 = zero4, hi1 = zero4, hi2 = zero4, hi3 = zero4;
    lo0 = MFMA(ha[0], bhh[0][0], lo0, 0, 0, 0);
    lo1 = MFMA(ha[0], bhh[1][0], lo1, 0, 0, 0);
    lo2 = MFMA(ha[0], bhh[2][0], lo2, 0, 0, 0);
    lo3 = MFMA(ha[0], bhh[3][0], lo3, 0, 0, 0);
    hi0 = MFMA(ha[2], bhh[0][2], hi0, 0, 0, 0);
    hi1 = MFMA(ha[2], bhh[1][2], hi1, 0, 0, 0);
    hi2 = MFMA(ha[2], bhh[2][2], hi2, 0, 0, 0);
    hi3 = MFMA(ha[2], bhh[3][2], hi3, 0, 0, 0);
    lo0 = MFMA(ha[1], bhh[0][1], lo0, 0, 0, 0);
    lo1 = MFMA(ha[1], bhh[1][1], lo1, 0, 0, 0);
    lo2 = MFMA(ha[1], bhh[2][1], lo2, 0, 0, 0);
    lo3 = MFMA(ha[1], bhh[3][1], lo3, 0, 0, 0);
    hi0 = MFMA(ha[3], bhh[0][3], hi0, 0, 0, 0);
    hi1 = MFMA(ha[3], bhh[1][3], hi1, 0, 0, 0);
    hi2 = MFMA(ha[3], bhh[2][3], hi2, 0, 0, 0);
    hi3 = MFMA(ha[3], bhh[3][3], hi3, 0, 0, 0);

    // fc1 for slice t-1 with stale ha (= h_{t-1}): fills MFMA pipe during activations
    facc = MFMA(ha[0], fbh0, facc, 0, 0, 0);
    facc = MFMA(ha[1], fbh1, facc, 0, 0, 0);
    facc = MFMA(ha[2], fbh2, facc, 0, 0, 0);
    facc = MFMA(ha[3], fbh3, facc, 0, 0, 0);

    f32x4 acc0 = lo0 + hi0;
    f32x4 acc1 = lo1 + hi1;
    f32x4 acc2 = lo2 + hi2;
    f32x4 acc3 = lo3 + hi3;

    fbh0 = nfb0; fbh1 = nfb1; fbh2 = nfb2; fbh3 = nfb3;
    // next xa (LDS broadcast read; consumed in the post-store tail)
    int tn = (t + 1 < T_LEN) ? t + 1 : t;
    short8 xan = *(const short8*)(xab + tn * 256 + lc * 16);

    // activations: q-pair rcp batching (26 trans/lane), packed bf16 converts
    unsigned char* hw = h_lds + (t & 1) * 4096;
#pragma unroll
    for (int qp = 0; qp < 2; ++qp) {
      const int q0 = qp * 2, q1 = q0 + 1;
      float ea0 = __builtin_amdgcn_exp2f(acc0[q0]), ea1 = __builtin_amdgcn_exp2f(acc0[q1]);
      float eb0 = __builtin_amdgcn_exp2f(acc1[q0]), eb1 = __builtin_amdgcn_exp2f(acc1[q1]);
      float ec0 = __builtin_amdgcn_exp2f(acc2[q0]), ec1 = __builtin_amdgcn_exp2f(acc2[q1]);
      float ed0 = __builtin_amdgcn_exp2f(acc3[q0]), ed1 = __builtin_amdgcn_exp2f(acc3[q1]);
      float a0 = 1.f + ea0, b0 = 1.f + eb0, d0 = 1.f + ec0, e0 = 1.f + ed0;
      float a1 = 1.f + ea1, b1 = 1.f + eb1, d1 = 1.f + ec1, e1 = 1.f + ed1;
      float ab0 = a0 * b0, ab1 = a1 * b1, de0 = d0 * e0, de1 = d1 * e1;
      float rAB = __builtin_amdgcn_rcpf(ab0 * ab1);
      float rDE = __builtin_amdgcn_rcpf(de0 * de1);
      float rab0 = rAB * ab1, rab1 = rAB * ab0;
      float rde0 = rDE * de1, rde1 = rDE * de0;
      float iv0 = b0 * rab0, fv0 = a0 * rab0;
      float iv1 = b1 * rab1, fv1 = a1 * rab1;
      float gv0 = 1.f - 2.f * (e0 * rde0), ov0 = d0 * rde0;
      float gv1 = 1.f - 2.f * (e1 * rde1), ov1 = d1 * rde1;
      float cn0 = fv0 * c_reg[q0] + iv0 * gv0;
      float cn1 = fv1 * c_reg[q1] + iv1 * gv1;
      c_reg[q0] = cn0; c_reg[q1] = cn1;
      float et0 = __builtin_amdgcn_exp2f(2.8853900817779268f * cn0);
      float et1 = __builtin_amdgcn_exp2f(2.8853900817779268f * cn1);
      float t0 = 1.f + et0, t1 = 1.f + et1;
      float rT = __builtin_amdgcn_rcpf(t0 * t1);
      float hv0 = ov0 * (1.f - 2.f * (rT * t1));
      float hv1 = ov1 * (1.f - 2.f * (rT * t0));
      unsigned pk = cvt_pk_bf16(hv0, hv1);
      *(unsigned short*)(hw + soff[q0]) = (unsigned short)pk;
      *(unsigned short*)(hw + soff[q1]) = (unsigned short)(pk >> 16);
    }
    __builtin_amdgcn_s_setprio(0);

    // tail before barrier: precompute next step's x-part of gates
    accX0 = MFMA(xan, bxb[0], zero4, 0, 0, 0);
    accX1 = MFMA(xan, bxb[1], zero4, 0, 0, 0);
    accX2 = MFMA(xan, bxb[2], zero4, 0, 0, 0);
    accX3 = MFMA(xan, bxb[3], zero4, 0, 0, 0);

    BAR();   // h_t complete

    // read h_t fragments -> straight into next step's gate chains
#pragma unroll
    for (int kk = 0; kk < 4; ++kk)
      ha[kk] = *(const short8*)(hw + lc * 256 + ((kk * 64 + lq * 16) ^ SWZ(lc)));
  }
  // final fc1 term: F_119 with h_119 (ha holds h_119 after last barrier)
  facc = MFMA(ha[0], fbh0, facc, 0, 0, 0);
  facc = MFMA(ha[1], fbh1, facc, 0, 0, 0);
  facc = MFMA(ha[2], fbh2, facc, 0, 0, 0);
  facc = MFMA(ha[3], fbh3, facc, 0, 0, 0);

  // ---- epilogue: bias+ReLU -> fc2 -> log_softmax ----
  float bias = FC1B[hcol];
  __syncthreads();                 // everyone out of the loop; xab free
  float* hid = (float*)xab;        // [16][132] padded
#pragma unroll
  for (int q = 0; q < 4; ++q) {
    float v = facc[q] + bias;
    hid[(lq * 4 + q) * 132 + hcol] = v > 0.f ? v : 0.f;
  }
  __syncthreads();
  if (tid < 160) {
    int r = tid & 15, k = tid >> 4;
    float a = fc2b_s[k];
#pragma unroll 4
    for (int j = 0; j < 100; ++j) a += hid[r * 132 + j] * fc2w_s[k * 100 + j];
    logit_s[r * 12 + k] = a;
  }
  __syncthreads();
  if (tid < 16) {
    int r = tid;
    float m = logit_s[r * 12];
#pragma unroll
    for (int k = 1; k < 10; ++k) m = fmaxf(m, logit_s[r * 12 + k]);
    float s = 0.f;
#pragma unroll
    for (int k = 0; k < 10; ++k)
      s += __builtin_amdgcn_exp2f(L2E * (logit_s[r * 12 + k] - m));
    float ls = __builtin_amdgcn_logf(s) * 0.6931471805599453f;
#pragma unroll
    for (int k = 0; k < 10; ++k)
      out[(r0 + r) * 10 + k] = logit_s[r * 12 + k] - m - ls;
  }
}

extern "C" void kernel_launch(void* const* d_in, const int* in_sizes, int n_in,
                              void* d_out, int out_size, void* d_ws, size_t ws_size,
                              hipStream_t stream) {
  const float* x     = (const float*)d_in[0];
  const float* h0    = (const float*)d_in[1];
  const float* c0    = (const float*)d_in[2];
  const float* W_ih  = (const float*)d_in[3];
  const float* W_hh  = (const float*)d_in[4];
  const float* b_ih  = (const float*)d_in[5];
  const float* b_hh  = (const float*)d_in[6];
  const float* fc1_w = (const float*)d_in[7];
  const float* fc1_b = (const float*)d_in[8];
  const float* fc2_w = (const float*)d_in[9];
  const float* fc2_b = (const float*)d_in[10];
  float* out = (float*)d_out;
  unsigned char* ws = (unsigned char*)d_ws;

  prep_all<<<1032, 256, 0, stream>>>(W_ih, W_hh, b_ih, b_hh, fc1_w, fc1_b, ws);
  lstm_fused<<<256, 512, 0, stream>>>(x, h0, c0, fc2_w, fc2_b, ws, out);
}

// Round 10
// 136.083 us; speedup vs baseline: 7.7114x; 1.0372x over previous
//
#include <hip/hip_runtime.h>

// Problem constants
#define T_LEN 120
#define H 128
#define ROWS 16          // batch rows per block
#define FC1_STRIDE 15360 // T*H

// workspace layout (bytes)
#define OFF_WHH   0u        // [512][128] bf16, pre-scaled by gate constant
#define OFF_WXB   131072u   // [512][32]  bf16 (W_ih cols 0-3, bias col 4), pre-scaled
#define OFF_FC1W  163840u   // [128][15360] bf16 (rows >=100 zero)
#define OFF_FC1B  4096000u  // [128] f32 (zero-padded)

typedef short short8 __attribute__((ext_vector_type(8)));   // 8 bf16 in 4 VGPRs
typedef float f32x4 __attribute__((ext_vector_type(4)));
typedef float f32x2 __attribute__((ext_vector_type(2)));    // packed-f32 pair (v_pk_*)
typedef unsigned int ui32x4 __attribute__((ext_vector_type(4)));

#define L2E 1.4426950408889634f
#define SWZ(r) (((((r) & 7) ^ (((r) >> 3) << 1))) << 4)
#define MFMA __builtin_amdgcn_mfma_f32_16x16x32_bf16

__device__ __forceinline__ unsigned short f2bu(float f) {   // f32 -> bf16 (RNE)
  unsigned u = __builtin_bit_cast(unsigned, f);
  u += 0x7fffu + ((u >> 16) & 1u);
  return (unsigned short)(u >> 16);
}
__device__ __forceinline__ unsigned cvt_pk_bf16(float lo, float hi) { // 2xf32 -> packed bf16 (RNE)
  unsigned r;
  asm("v_cvt_pk_bf16_f32 %0, %1, %2" : "=v"(r) : "v"(lo), "v"(hi));
  return r;
}
__device__ __forceinline__ float gate_scale(int row) {
  // rows 0-127: i, 128-255: f, 256-383: g, 384-511: o
  return ((row >> 7) == 2) ? 2.0f * L2E : -L2E;
}

// ---- one-time weight conversion (single launch) ----
__global__ void prep_all(const float* __restrict__ W_ih, const float* __restrict__ W_hh,
                         const float* __restrict__ b_ih, const float* __restrict__ b_hh,
                         const float* __restrict__ fc1_w, const float* __restrict__ fc1_b,
                         unsigned char* __restrict__ ws) {
  if (blockIdx.x < 1024) {
    unsigned short* w = (unsigned short*)(ws + OFF_FC1W);
    int j = blockIdx.x >> 3;
    int c0 = ((blockIdx.x & 7) * 256 + threadIdx.x) * 8;
    if (c0 >= FC1_STRIDE) return;
    short8 v = {0, 0, 0, 0, 0, 0, 0, 0};
    if (j < 100) {
      const float* src = fc1_w + j * FC1_STRIDE + c0;
#pragma unroll
      for (int e = 0; e < 8; ++e) ((unsigned short*)&v)[e] = f2bu(src[e]);
    }
    *(short8*)(w + j * FC1_STRIDE + c0) = v;
  } else {
    unsigned short* whh = (unsigned short*)(ws + OFF_WHH);
    unsigned short* wxb = (unsigned short*)(ws + OFF_WXB);
    float* fb = (float*)(ws + OFF_FC1B);
    int tid = (blockIdx.x - 1024) * 256 + threadIdx.x;
    const int nt = 8 * 256;
    for (int i = tid; i < 512 * 128; i += nt) {
      int row = i >> 7;
      whh[i] = f2bu(W_hh[i] * gate_scale(row));
    }
    for (int i = tid; i < 512 * 32; i += nt) {
      int j = i >> 5, k = i & 31;
      float s = gate_scale(j);
      float v = 0.f;
      if (k < 4) v = W_ih[j * 4 + k] * s;
      else if (k == 4) v = (b_ih[j] + b_hh[j]) * s;
      wxb[i] = f2bu(v);
    }
    for (int i = tid; i < 128; i += nt) fb[i] = (i < 100) ? fc1_b[i] : 0.f;
  }
}

// ---- fused persistent kernel: 256 blocks x 512 threads ----
__global__ __launch_bounds__(512, 2)
void lstm_fused(const float* __restrict__ x, const float* __restrict__ h0,
                const float* __restrict__ c0, const float* __restrict__ fc2_w,
                const float* __restrict__ fc2_b, const unsigned char* __restrict__ ws,
                float* __restrict__ out) {
  __shared__ __align__(16) unsigned char xab[T_LEN * 256];      // packed x A-frags; reused as hid[16][132] f32
  __shared__ __align__(16) unsigned char h_lds[2 * 4096];       // double-buffered bf16 h (16 rows x 256B, swizzled)
  __shared__ __align__(16) float fc2w_s[1000];
  __shared__ float fc2b_s[10];
  __shared__ float logit_s[ROWS * 12];

  const int tid = threadIdx.x;
  const int w = tid >> 6;
  const int l = tid & 63;
  const int lq = l >> 4;
  const int lc = l & 15;
  const int r0 = blockIdx.x * ROWS;
  const int hcol = w * 16 + lc;

  const unsigned short* Whh = (const unsigned short*)(ws + OFF_WHH);
  const unsigned short* Wxb = (const unsigned short*)(ws + OFF_WXB);
  const unsigned short* FC1 = (const unsigned short*)(ws + OFF_FC1W);
  const float* FC1B = (const float*)(ws + OFF_FC1B);

  // stage fc2 weights
  for (int i = tid; i < 1000; i += 512) fc2w_s[i] = fc2_w[i];
  if (tid < 10) fc2b_s[tid] = fc2_b[tid];

  // pre-pack x A-frags for all t: slot (t,row) = 16B {x0,x1,x2,x3,1.0,0,0,0} bf16
  for (int i = tid; i < ROWS * T_LEN; i += 512) {
    int rr = i / T_LEN, t = i - rr * T_LEN;
    f32x4 xv = *(const f32x4*)(x + (r0 + rr) * (T_LEN * 4) + t * 4);
    unsigned w0 = cvt_pk_bf16(xv[0], xv[1]);
    unsigned w1 = cvt_pk_bf16(xv[2], xv[3]);
    ui32x4 pk = {w0, w1, 0x3f80u, 0u};
    *(ui32x4*)(xab + t * 256 + rr * 16) = pk;
  }
  // stage h0 -> buffer 1 (loop t=0 writes buffer 0)
  for (int e = tid * 2; e < ROWS * H; e += 1024) {
    int r = e >> 7, c = e & 127;
    unsigned u = (unsigned)f2bu(h0[(r0 + r) * H + c]) |
                 ((unsigned)f2bu(h0[(r0 + r) * H + c + 1]) << 16);
    *(unsigned*)(h_lds + 4096 + r * 256 + ((2 * c) ^ SWZ(r))) = u;
  }
  // c0: lane owns rows lq*4+q, col hcol
  float c_reg[4];
#pragma unroll
  for (int q = 0; q < 4; ++q) c_reg[q] = c0[(r0 + lq * 4 + q) * H + hcol];

  // register-resident B fragments; wave w owns gate tiles {w, 8+w, 16+w, 24+w}
  short8 bhh[4][4], bxb[4];
#pragma unroll
  for (int g = 0; g < 4; ++g) {
    int n0 = (g * 8 + w) * 16;
#pragma unroll
    for (int kk = 0; kk < 4; ++kk)
      bhh[g][kk] = *(const short8*)(Whh + (n0 + lc) * H + kk * 32 + lq * 8);
    bxb[g] = *(const short8*)(Wxb + (n0 + lc) * 32 + lq * 8);
  }
  const unsigned short* fc1row = FC1 + (w * 16 + lc) * FC1_STRIDE;
  f32x4 facc = {0.f, 0.f, 0.f, 0.f};

  // precomputed swizzled h-store byte offsets for q=0..3
  unsigned soff[4];
#pragma unroll
  for (int q = 0; q < 4; ++q) {
    int r = lq * 4 + q;
    soff[q] = (unsigned)(r * 256 + ((2 * hcol) ^ SWZ(r)));
  }

  __syncthreads();

  // initial A fragments (h0, buffer 1) + xa(t=0) + accX(t=0)
  short8 ha[4];
#pragma unroll
  for (int kk = 0; kk < 4; ++kk)
    ha[kk] = *(const short8*)(h_lds + 4096 + lc * 256 + ((kk * 64 + lq * 16) ^ SWZ(lc)));
  short8 xa = *(const short8*)(xab + lc * 16);

  const f32x4 zero4 = {0.f, 0.f, 0.f, 0.f};
  f32x4 accX0 = MFMA(xa, bxb[0], zero4, 0, 0, 0);
  f32x4 accX1 = MFMA(xa, bxb[1], zero4, 0, 0, 0);
  f32x4 accX2 = MFMA(xa, bxb[2], zero4, 0, 0, 0);
  f32x4 accX3 = MFMA(xa, bxb[3], zero4, 0, 0, 0);

  // fc1 B-frags held one step behind (zero for t=0: first pre-barrier fc1 MFMA adds 0)
  short8 fbh0 = {0,0,0,0,0,0,0,0}, fbh1 = {0,0,0,0,0,0,0,0};
  short8 fbh2 = {0,0,0,0,0,0,0,0}, fbh3 = {0,0,0,0,0,0,0,0};

  const f32x2 one2 = {1.f, 1.f};

#pragma unroll 2
  for (int t = 0; t < T_LEN; ++t) {
    // fb for slice t: issue VMEM first (independent; consumed next iteration)
    const unsigned short* fp = fc1row + t * 128 + lq * 8;
    short8 nfb0 = *(const short8*)(fp + 0);
    short8 nfb1 = *(const short8*)(fp + 32);
    short8 nfb2 = *(const short8*)(fp + 64);
    short8 nfb3 = *(const short8*)(fp + 96);

    // --- critical section: gates (split chains, depth 3) + activations ---
    __builtin_amdgcn_s_setprio(1);
    f32x4 lo0 = accX0, lo1 = accX1, lo2 = accX2, lo3 = accX3;
    f32x4 hi0 = zero4, hi1 = zero4, hi2 = zero4, hi3 = zero4;
    lo0 = MFMA(ha[0], bhh[0][0], lo0, 0, 0, 0);
    lo1 = MFMA(ha[0], bhh[1][0], lo1, 0, 0, 0);
    lo2 = MFMA(ha[0], bhh[2][0], lo2, 0, 0, 0);
    lo3 = MFMA(ha[0], bhh[3][0], lo3, 0, 0, 0);
    hi0 = MFMA(ha[2], bhh[0][2], hi0, 0, 0, 0);
    hi1 = MFMA(ha[2], bhh[1][2], hi1, 0, 0, 0);
    hi2 = MFMA(ha[2], bhh[2][2], hi2, 0, 0, 0);
    hi3 = MFMA(ha[2], bhh[3][2], hi3, 0, 0, 0);
    lo0 = MFMA(ha[1], bhh[0][1], lo0, 0, 0, 0);
    lo1 = MFMA(ha[1], bhh[1][1], lo1, 0, 0, 0);
    lo2 = MFMA(ha[1], bhh[2][1], lo2, 0, 0, 0);
    lo3 = MFMA(ha[1], bhh[3][1], lo3, 0, 0, 0);
    hi0 = MFMA(ha[3], bhh[0][3], hi0, 0, 0, 0);
    hi1 = MFMA(ha[3], bhh[1][3], hi1, 0, 0, 0);
    hi2 = MFMA(ha[3], bhh[2][3], hi2, 0, 0, 0);
    hi3 = MFMA(ha[3], bhh[3][3], hi3, 0, 0, 0);

    // fc1 for slice t-1 with stale ha (= h_{t-1}): fills MFMA pipe during activations
    facc = MFMA(ha[0], fbh0, facc, 0, 0, 0);
    facc = MFMA(ha[1], fbh1, facc, 0, 0, 0);
    facc = MFMA(ha[2], fbh2, facc, 0, 0, 0);
    facc = MFMA(ha[3], fbh3, facc, 0, 0, 0);

    f32x4 acc0 = lo0 + hi0;
    f32x4 acc1 = lo1 + hi1;
    f32x4 acc2 = lo2 + hi2;
    f32x4 acc3 = lo3 + hi3;

    fbh0 = nfb0; fbh1 = nfb1; fbh2 = nfb2; fbh3 = nfb3;
    // next xa (LDS broadcast read; consumed post-barrier by accX)
    int tn = (t + 1 < T_LEN) ? t + 1 : t;
    short8 xan = *(const short8*)(xab + tn * 256 + lc * 16);

    // activations: q-pair rcp batching (26 trans/lane), packed-f32 pair math
    unsigned char* hw = h_lds + (t & 1) * 4096;
#pragma unroll
    for (int qp = 0; qp < 2; ++qp) {
      const int q0 = qp * 2, q1 = q0 + 1;
      f32x2 ea = {__builtin_amdgcn_exp2f(acc0[q0]), __builtin_amdgcn_exp2f(acc0[q1])};
      f32x2 eb = {__builtin_amdgcn_exp2f(acc1[q0]), __builtin_amdgcn_exp2f(acc1[q1])};
      f32x2 ec = {__builtin_amdgcn_exp2f(acc2[q0]), __builtin_amdgcn_exp2f(acc2[q1])};
      f32x2 ed = {__builtin_amdgcn_exp2f(acc3[q0]), __builtin_amdgcn_exp2f(acc3[q1])};
      f32x2 a = ea + one2, b = eb + one2, d = ec + one2, e = ed + one2;
      f32x2 ab = a * b, de = d * e;
      float rAB = __builtin_amdgcn_rcpf(ab[0] * ab[1]);
      float rDE = __builtin_amdgcn_rcpf(de[0] * de[1]);
      f32x2 rab = {rAB * ab[1], rAB * ab[0]};
      f32x2 rde = {rDE * de[1], rDE * de[0]};
      f32x2 iv = b * rab, fv = a * rab;
      f32x2 erde = e * rde;
      f32x2 gv = one2 - (erde + erde);
      f32x2 ov = d * rde;
      f32x2 cp = {c_reg[q0], c_reg[q1]};
      f32x2 cn = fv * cp + iv * gv;
      c_reg[q0] = cn[0]; c_reg[q1] = cn[1];
      f32x2 cs = cn * 2.8853900817779268f;
      f32x2 et = {__builtin_amdgcn_exp2f(cs[0]), __builtin_amdgcn_exp2f(cs[1])};
      f32x2 tt = et + one2;
      float rT = __builtin_amdgcn_rcpf(tt[0] * tt[1]);
      float hv0 = ov[0] * (1.f - 2.f * (rT * tt[1]));
      float hv1 = ov[1] * (1.f - 2.f * (rT * tt[0]));
      unsigned pk = cvt_pk_bf16(hv0, hv1);
      *(unsigned short*)(hw + soff[q0]) = (unsigned short)pk;
      *(unsigned short*)(hw + soff[q1]) = (unsigned short)(pk >> 16);
    }
    __builtin_amdgcn_s_setprio(0);

    // barrier immediately after stores: shortest possible arrival tail
    asm volatile("s_waitcnt lgkmcnt(0)" ::: "memory");
    __builtin_amdgcn_s_barrier();
    asm volatile("" ::: "memory");

    // post-barrier: issue ha reads, then accX MFMAs inside the read-latency shadow
#pragma unroll
    for (int kk = 0; kk < 4; ++kk)
      ha[kk] = *(const short8*)(hw + lc * 256 + ((kk * 64 + lq * 16) ^ SWZ(lc)));
    accX0 = MFMA(xan, bxb[0], zero4, 0, 0, 0);
    accX1 = MFMA(xan, bxb[1], zero4, 0, 0, 0);
    accX2 = MFMA(xan, bxb[2], zero4, 0, 0, 0);
    accX3 = MFMA(xan, bxb[3], zero4, 0, 0, 0);
  }
  // final fc1 term: F_119 with h_119 (ha holds h_119 after last barrier)
  facc = MFMA(ha[0], fbh0, facc, 0, 0, 0);
  facc = MFMA(ha[1], fbh1, facc, 0, 0, 0);
  facc = MFMA(ha[2], fbh2, facc, 0, 0, 0);
  facc = MFMA(ha[3], fbh3, facc, 0, 0, 0);

  // ---- epilogue: bias+ReLU -> fc2 -> log_softmax ----
  float bias = FC1B[hcol];
  __syncthreads();                 // everyone out of the loop; xab free
  float* hid = (float*)xab;        // [16][132] padded
#pragma unroll
  for (int q = 0; q < 4; ++q) {
    float v = facc[q] + bias;
    hid[(lq * 4 + q) * 132 + hcol] = v > 0.f ? v : 0.f;
  }
  __syncthreads();
  if (tid < 160) {
    int r = tid & 15, k = tid >> 4;
    float a = fc2b_s[k];
#pragma unroll 4
    for (int j = 0; j < 100; ++j) a += hid[r * 132 + j] * fc2w_s[k * 100 + j];
    logit_s[r * 12 + k] = a;
  }
  __syncthreads();
  if (tid < 16) {
    int r = tid;
    float m = logit_s[r * 12];
#pragma unroll
    for (int k = 1; k < 10; ++k) m = fmaxf(m, logit_s[r * 12 + k]);
    float s = 0.f;
#pragma unroll
    for (int k = 0; k < 10; ++k)
      s += __builtin_amdgcn_exp2f(L2E * (logit_s[r * 12 + k] - m));
    float ls = __builtin_amdgcn_logf(s) * 0.6931471805599453f;
#pragma unroll
    for (int k = 0; k < 10; ++k)
      out[(r0 + r) * 10 + k] = logit_s[r * 12 + k] - m - ls;
  }
}

extern "C" void kernel_launch(void* const* d_in, const int* in_sizes, int n_in,
                              void* d_out, int out_size, void* d_ws, size_t ws_size,
                              hipStream_t stream) {
  const float* x     = (const float*)d_in[0];
  const float* h0    = (const float*)d_in[1];
  const float* c0    = (const float*)d_in[2];
  const float* W_ih  = (const float*)d_in[3];
  const float* W_hh  = (const float*)d_in[4];
  const float* b_ih  = (const float*)d_in[5];
  const float* b_hh  = (const float*)d_in[6];
  const float* fc1_w = (const float*)d_in[7];
  const float* fc1_b = (const float*)d_in[8];
  const float* fc2_w = (const float*)d_in[9];
  const float* fc2_b = (const float*)d_in[10];
  float* out = (float*)d_out;
  unsigned char* ws = (unsigned char*)d_ws;

  prep_all<<<1032, 256, 0, stream>>>(W_ih, W_hh, b_ih, b_hh, fc1_w, fc1_b, ws);
  lstm_fused<<<256, 512, 0, stream>>>(x, h0, c0, fc2_w, fc2_b, ws, out);
}